// Round 1
// baseline (1051.277 us; speedup 1.0000x reference)
//
#include <hip/hip_runtime.h>

#define H 64
#define NA 65536
#define NB 131072
#define NM 16384
#define NC 2048

// ---------------- input projection: out[N,64] = x[N,K] @ W[K,64] + b ----------------
template<int K>
__global__ __launch_bounds__(256) void proj_kernel(
    const float* __restrict__ x, const float* __restrict__ W,
    const float* __restrict__ b, float* __restrict__ out, int N)
{
    __shared__ float Wl[K * H];
    for (int i = threadIdx.x; i < K * H; i += 256) Wl[i] = W[i];
    __syncthreads();
    int row = blockIdx.x * 4 + (threadIdx.x >> 6);
    int col = threadIdx.x & 63;
    if (row >= N) return;
    const float* xr = x + (size_t)row * K;
    float acc = b[col];
    #pragma unroll
    for (int k = 0; k < K; ++k) acc = fmaf(xr[k], Wl[k * H + col], acc);
    out[(size_t)row * H + col] = acc;
}

// ---------------- init cell accumulator to 3*x_cell (residual added 3x: ac,bc,mc) ----
__global__ __launch_bounds__(256) void init_cell_kernel(
    const float* __restrict__ xc, float* __restrict__ acc, int n)
{
    int i = blockIdx.x * 256 + threadIdx.x;
    if (i < n) acc[i] = 3.0f * xc[i];
}

// ---------------- edge kernel: one thread = one edge ----------------
// z = [x_cell[dst] (64), src_feat[src] (64)];  msg = sigmoid(z@Wf+bf)*softplus(z@Ws+bs)
// atomic segment-sum into acc_cell[dst].
__device__ __forceinline__ void accum_part(
    const float* __restrict__ z,      // 64 floats (one half of z), 16B-aligned
    const float* __restrict__ Wfp,    // Wf + krow0*H + c0 (wave-uniform)
    const float* __restrict__ Wsp,
    float accf[32], float accs[32])
{
    for (int kc = 0; kc < 16; ++kc) {
        float4 zv = *(const float4*)(z + kc * 4);
        const float* wf = Wfp + kc * 4 * H;
        const float* ws = Wsp + kc * 4 * H;
        #pragma unroll
        for (int j = 0; j < 4; ++j) {
            float a = (&zv.x)[j];
            #pragma unroll
            for (int c = 0; c < 32; ++c) {
                accf[c] = fmaf(a, wf[j * H + c], accf[c]);
                accs[c] = fmaf(a, ws[j * H + c], accs[c]);
            }
        }
    }
}

__global__ __launch_bounds__(256) void edge_kernel(
    const float* __restrict__ src_feat, const float* __restrict__ x_cell,
    const int* __restrict__ edges, int E,
    const float* __restrict__ Wf, const float* __restrict__ bf,
    const float* __restrict__ Ws, const float* __restrict__ bs,
    float* __restrict__ acc_cell)
{
    int tid = blockIdx.x * 256 + threadIdx.x;
    int stride = gridDim.x * 256;
    for (int e = tid; e < E; e += stride) {
        int s = edges[e];
        int d = edges[E + e];
        const float* zi = x_cell + (size_t)d * H;     // z[0:64]
        const float* zj = src_feat + (size_t)s * H;   // z[64:128]
        #pragma unroll
        for (int half = 0; half < 2; ++half) {        // output cols in 2 chunks of 32
            int c0 = half * 32;
            float accf[32], accs[32];
            #pragma unroll
            for (int c = 0; c < 32; ++c) { accf[c] = bf[c0 + c]; accs[c] = bs[c0 + c]; }
            accum_part(zi, Wf + c0,         Ws + c0,         accf, accs);
            accum_part(zj, Wf + H * H + c0, Ws + H * H + c0, accf, accs);
            #pragma unroll
            for (int c = 0; c < 32; ++c) {
                float f = accf[c];
                float sv = accs[c];
                float sg = 1.0f / (1.0f + __expf(-f));
                float sp = fmaxf(sv, 0.0f) + __logf(1.0f + __expf(-fabsf(sv)));
                atomicAdd(&acc_cell[(size_t)d * H + c0 + c], sg * sp);
            }
        }
    }
}

// ---------------- head: out[c] = softplus(relu(acc[c]) @ Wp + bp) @ Wo + bo ----------
__global__ __launch_bounds__(256) void head_kernel(
    const float* __restrict__ acc_cell,
    const float* __restrict__ Wp, const float* __restrict__ bp,
    const float* __restrict__ Wo, const float* __restrict__ bo,
    float* __restrict__ out, int n)
{
    int c = blockIdx.x * 256 + threadIdx.x;
    if (c >= n) return;
    float v[H];
    #pragma unroll
    for (int k = 0; k < H; ++k) v[k] = fmaxf(acc_cell[(size_t)c * H + k], 0.0f);
    float o = bo[0];
    for (int j = 0; j < H; ++j) {   // j wave-uniform -> Wp/Wo loads scalarize
        float a = bp[j];
        #pragma unroll
        for (int k = 0; k < H; ++k) a = fmaf(v[k], Wp[k * H + j], a);
        float sp = fmaxf(a, 0.0f) + __logf(1.0f + __expf(-fabsf(a)));
        o = fmaf(sp, Wo[j], o);
    }
    out[c] = o;
}

extern "C" void kernel_launch(void* const* d_in, const int* in_sizes, int n_in,
                              void* d_out, int out_size, void* d_ws, size_t ws_size,
                              hipStream_t stream)
{
    const float* x_atom  = (const float*)d_in[0];
    const float* x_bond  = (const float*)d_in[1];
    const float* x_motif = (const float*)d_in[2];
    const float* x_cell  = (const float*)d_in[3];
    const float* Wa = (const float*)d_in[4];
    const float* ba = (const float*)d_in[5];
    const float* Wb = (const float*)d_in[6];
    const float* bb = (const float*)d_in[7];
    const float* Wm = (const float*)d_in[8];
    const float* bm = (const float*)d_in[9];
    const float* Wf = (const float*)d_in[10];
    const float* bf = (const float*)d_in[11];
    const float* Ws = (const float*)d_in[12];
    const float* bs = (const float*)d_in[13];
    const float* Wp = (const float*)d_in[14];
    const float* bp = (const float*)d_in[15];
    const float* Wo = (const float*)d_in[16];
    const float* bo = (const float*)d_in[17];
    // edges: 18..26 = aa,ab,am,bb,bm,mm,ac,bc,mc ; only cell-targeting ones matter
    const int* e_ac = (const int*)d_in[24];
    const int* e_bc = (const int*)d_in[25];
    const int* e_mc = (const int*)d_in[26];

    // workspace layout (floats): proj_atom | proj_bond | proj_motif | acc_cell
    float* pa = (float*)d_ws;
    float* pb = pa + (size_t)NA * H;
    float* pm = pb + (size_t)NB * H;
    float* pc = pm + (size_t)NM * H;
    float* out = (float*)d_out;

    proj_kernel<92><<<NA / 4, 256, 0, stream>>>(x_atom,  Wa, ba, pa, NA);
    proj_kernel<7> <<<NB / 4, 256, 0, stream>>>(x_bond,  Wb, bb, pb, NB);
    proj_kernel<35><<<NM / 4, 256, 0, stream>>>(x_motif, Wm, bm, pm, NM);
    init_cell_kernel<<<(NC * H) / 256, 256, 0, stream>>>(x_cell, pc, NC * H);

    const int E_ac = 65536, E_bc = 131072, E_mc = 16384;
    const int roff_ac = 6, roff_bc = 7, roff_mc = 8;   // indices in REL_ORDER
    edge_kernel<<<E_ac / 256, 256, 0, stream>>>(pa, x_cell, e_ac, E_ac,
        Wf + (size_t)roff_ac * 2 * H * H, bf + roff_ac * H,
        Ws + (size_t)roff_ac * 2 * H * H, bs + roff_ac * H, pc);
    edge_kernel<<<E_bc / 256, 256, 0, stream>>>(pb, x_cell, e_bc, E_bc,
        Wf + (size_t)roff_bc * 2 * H * H, bf + roff_bc * H,
        Ws + (size_t)roff_bc * 2 * H * H, bs + roff_bc * H, pc);
    edge_kernel<<<E_mc / 256, 256, 0, stream>>>(pm, x_cell, e_mc, E_mc,
        Wf + (size_t)roff_mc * 2 * H * H, bf + roff_mc * H,
        Ws + (size_t)roff_mc * 2 * H * H, bs + roff_mc * H, pc);

    head_kernel<<<NC / 256, 256, 0, stream>>>(pc, Wp, bp, Wo, bo, out, NC);
}

// Round 2
// 518.310 us; speedup vs baseline: 2.0283x; 2.0283x over previous
//
#include <hip/hip_runtime.h>

#define H 64
#define NA 65536
#define NB 131072
#define NM 16384
#define NC 2048
#define E_AC 65536
#define E_BC 131072
#define E_MC 16384
#define NE_TOT (E_AC + E_BC + E_MC)
#define NBKT (3 * NC)
#define CHUNK 32768

__device__ __forceinline__ float sigmoidf(float x) { return 1.0f / (1.0f + __expf(-x)); }
__device__ __forceinline__ float softplusf(float x) {
    return fmaxf(x, 0.0f) + __logf(1.0f + __expf(-fabsf(x)));
}

// ---------- zero counts + partials ----------
__global__ __launch_bounds__(256) void zero_kernel(float* partial, int* counts) {
    int i = blockIdx.x * 256 + threadIdx.x;
    if (i < 6 * NC * H) partial[i] = 0.0f;
    if (i < NBKT) counts[i] = 0;
}

// ---------- CSR build ----------
__global__ __launch_bounds__(256) void count_kernel(
    const int* __restrict__ ea, const int* __restrict__ eb, const int* __restrict__ em,
    int* __restrict__ counts)
{
    int i = blockIdx.x * 256 + threadIdx.x;
    int r, d;
    if (i < E_AC)                { r = 0; d = ea[E_AC + i]; }
    else if (i < E_AC + E_BC)    { r = 1; d = eb[E_BC + (i - E_AC)]; }
    else if (i < NE_TOT)         { r = 2; d = em[E_MC + (i - E_AC - E_BC)]; }
    else return;
    atomicAdd(&counts[r * NC + d], 1);
}

__global__ __launch_bounds__(1024) void scan_kernel(
    const int* __restrict__ cnt, int* __restrict__ off, int* __restrict__ cur)
{
    __shared__ int ps[1024];
    int t = threadIdx.x;
    int v[6], loc[6], s = 0;
    #pragma unroll
    for (int i = 0; i < 6; ++i) v[i] = cnt[t * 6 + i];
    #pragma unroll
    for (int i = 0; i < 6; ++i) { loc[i] = s; s += v[i]; }
    ps[t] = s;
    __syncthreads();
    for (int d = 1; d < 1024; d <<= 1) {
        int val = (t >= d) ? ps[t - d] : 0;
        __syncthreads();
        ps[t] += val;
        __syncthreads();
    }
    int base = (t > 0) ? ps[t - 1] : 0;
    #pragma unroll
    for (int i = 0; i < 6; ++i) { int o = base + loc[i]; off[t * 6 + i] = o; cur[t * 6 + i] = o; }
    if (t == 1023) off[NBKT] = ps[1023];
}

__global__ __launch_bounds__(256) void scatter_kernel(
    const int* __restrict__ ea, const int* __restrict__ eb, const int* __restrict__ em,
    int* __restrict__ cur, int* __restrict__ sorted)
{
    int i = blockIdx.x * 256 + threadIdx.x;
    int r, d, s;
    if (i < E_AC)                { r = 0; s = ea[i];               d = ea[E_AC + i]; }
    else if (i < E_AC + E_BC)    { int k = i - E_AC; r = 1; s = eb[k]; d = eb[E_BC + k]; }
    else if (i < NE_TOT)         { int k = i - E_AC - E_BC; r = 2; s = em[k]; d = em[E_MC + k]; }
    else return;
    int pos = atomicAdd(&cur[r * NC + d], 1);
    sorted[pos] = s;
}

// ---------- input projection: out[n,64] = x[n,K] @ W[K,64] + b ----------
template<int K>
__global__ __launch_bounds__(256) void proj_kernel(
    const float* __restrict__ x, const float* __restrict__ W,
    const float* __restrict__ b, float* __restrict__ out, int n)
{
    __shared__ float Wl[K * H];
    for (int i = threadIdx.x; i < K * H; i += 256) Wl[i] = W[i];
    __syncthreads();
    int row = blockIdx.x * 4 + (threadIdx.x >> 6);
    int col = threadIdx.x & 63;
    if (row >= n) return;
    const float* xr = x + (size_t)row * K;
    float acc = b[col];
    #pragma unroll
    for (int k = 0; k < K; ++k) acc = fmaf(xr[k], Wl[k * H + col], acc);
    out[(size_t)row * H + col] = acc;
}

// ---------- dst-side precompute: Cf/Cs[r][2048][64] = x_cell @ W_top + bias ----------
__global__ __launch_bounds__(256) void cellpart_kernel(
    const float* __restrict__ xc, const float* __restrict__ Wf, const float* __restrict__ bf,
    const float* __restrict__ Ws, const float* __restrict__ bs,
    float* __restrict__ Cf, float* __restrict__ Cs)
{
    int r = blockIdx.y;  // 0..2 -> relation 6+r
    const float* WfT = Wf + (size_t)(6 + r) * 2 * H * H;  // top half = rows 0..63
    const float* WsT = Ws + (size_t)(6 + r) * 2 * H * H;
    __shared__ float Wl[2][H * H];
    for (int i = threadIdx.x; i < H * H; i += 256) { Wl[0][i] = WfT[i]; Wl[1][i] = WsT[i]; }
    __syncthreads();
    int row = blockIdx.x * 4 + (threadIdx.x >> 6);
    int col = threadIdx.x & 63;
    const float* xr = xc + (size_t)row * H;
    float af = bf[(6 + r) * H + col], as = bs[(6 + r) * H + col];
    #pragma unroll
    for (int k = 0; k < H; ++k) {
        float xv = xr[k];
        af = fmaf(xv, Wl[0][k * H + col], af);
        as = fmaf(xv, Wl[1][k * H + col], as);
    }
    Cf[((size_t)r * NC + row) * H + col] = af;
    Cs[((size_t)r * NC + row) * H + col] = as;
}

// ---------- src-side precompute: Gf/Gs[n,64] = p[n,64] @ W_bot (W columns in VGPRs) ----
__global__ __launch_bounds__(256) void g_kernel(
    const float* __restrict__ p, const float* __restrict__ WfB, const float* __restrict__ WsB,
    float* __restrict__ gf, float* __restrict__ gs)
{
    __shared__ float pL[32 * H];  // 8 KB
    int col = threadIdx.x & 63;
    int q = threadIdx.x >> 6;
    int r0 = blockIdx.x * 32;
    float wf[64], ws[64];
    #pragma unroll
    for (int k = 0; k < 64; ++k) { wf[k] = WfB[k * H + col]; ws[k] = WsB[k * H + col]; }
    for (int i = threadIdx.x; i < 32 * H; i += 256) pL[i] = p[(size_t)r0 * H + i];
    __syncthreads();
    for (int row = q * 8; row < q * 8 + 8; ++row) {
        float af = 0.0f, as = 0.0f;
        #pragma unroll
        for (int kc = 0; kc < 16; ++kc) {
            float4 pv = *(const float4*)&pL[row * H + kc * 4];
            #pragma unroll
            for (int j = 0; j < 4; ++j) {
                float pe = (&pv.x)[j];
                af = fmaf(pe, wf[kc * 4 + j], af);
                as = fmaf(pe, ws[kc * 4 + j], as);
            }
        }
        gf[((size_t)r0 + row) * H + col] = af;
        gs[((size_t)r0 + row) * H + col] = as;
    }
}

// ---------- edge accumulate: wave per (bucket, half), no atomics ----------
__global__ __launch_bounds__(256) void accum_kernel(
    const float* __restrict__ gf, const float* __restrict__ gs,
    const int* __restrict__ sorted, const int* __restrict__ off,
    const float* __restrict__ Cf, const float* __restrict__ Cs,
    float* __restrict__ partial, int r, int lo, int hi)
{
    int wid = blockIdx.x * 4 + (threadIdx.x >> 6);  // 0..4095
    int lane = threadIdx.x & 63;
    int d = wid >> 1, sub = wid & 1;
    int g = r * NC + d;
    int j0 = off[g], j1 = off[g + 1];
    float cfv = Cf[(size_t)g * H + lane];
    float csv = Cs[(size_t)g * H + lane];
    float acc = 0.0f;
    for (int j = j0 + sub; j < j1; j += 8) {  // split-2 interleave, unroll-4
        int s0 = sorted[j];
        int s1 = (j + 2 < j1) ? sorted[j + 2] : -1;
        int s2 = (j + 4 < j1) ? sorted[j + 4] : -1;
        int s3 = (j + 6 < j1) ? sorted[j + 6] : -1;
        int ss[4] = {s0, s1, s2, s3};
        #pragma unroll
        for (int u = 0; u < 4; ++u) {
            int s = ss[u];
            if (s >= lo && s < hi) {  // wave-uniform branch
                int row = s - lo;
                float f  = cfv + gf[(size_t)row * H + lane];
                float sv = csv + gs[(size_t)row * H + lane];
                acc += sigmoidf(f) * softplusf(sv);
            }
        }
    }
    size_t pidx = (((size_t)sub * 3 + r) * NC + d) * H + lane;
    partial[pidx] += acc;  // same wave owns pidx across chunk launches
}

// ---------- head ----------
__global__ __launch_bounds__(256) void head_kernel(
    const float* __restrict__ partial, const float* __restrict__ xc,
    const float* __restrict__ Wp, const float* __restrict__ bp,
    const float* __restrict__ Wo, const float* __restrict__ bo,
    float* __restrict__ out)
{
    int c = blockIdx.x * 256 + threadIdx.x;
    if (c >= NC) return;
    float v[H];
    #pragma unroll
    for (int k = 0; k < H; ++k) {
        float a = 3.0f * xc[(size_t)c * H + k];
        #pragma unroll
        for (int t = 0; t < 6; ++t) a += partial[((size_t)t * NC + c) * H + k];
        v[k] = fmaxf(a, 0.0f);
    }
    float o = bo[0];
    for (int j = 0; j < H; ++j) {
        float a = bp[j];
        #pragma unroll
        for (int k = 0; k < H; ++k) a = fmaf(v[k], Wp[k * H + j], a);
        o = fmaf(softplusf(a), Wo[j], o);
    }
    out[c] = o;
}

extern "C" void kernel_launch(void* const* d_in, const int* in_sizes, int n_in,
                              void* d_out, int out_size, void* d_ws, size_t ws_size,
                              hipStream_t stream)
{
    const float* x_atom  = (const float*)d_in[0];
    const float* x_bond  = (const float*)d_in[1];
    const float* x_motif = (const float*)d_in[2];
    const float* x_cell  = (const float*)d_in[3];
    const float* Wa = (const float*)d_in[4];
    const float* ba = (const float*)d_in[5];
    const float* Wb = (const float*)d_in[6];
    const float* bb = (const float*)d_in[7];
    const float* Wm = (const float*)d_in[8];
    const float* bm = (const float*)d_in[9];
    const float* Wf = (const float*)d_in[10];
    const float* bf = (const float*)d_in[11];
    const float* Ws = (const float*)d_in[12];
    const float* bs = (const float*)d_in[13];
    const float* Wp = (const float*)d_in[14];
    const float* bp = (const float*)d_in[15];
    const float* Wo = (const float*)d_in[16];
    const float* bo = (const float*)d_in[17];
    const int* e_ac = (const int*)d_in[24];
    const int* e_bc = (const int*)d_in[25];
    const int* e_mc = (const int*)d_in[26];

    // ---- workspace layout (256B-aligned) ----
    char* base = (char*)d_ws;
    size_t o = 0;
    auto alloc = [&](size_t bytes) { char* r = base + o; o = (o + bytes + 255) & ~(size_t)255; return r; };
    float* partial = (float*)alloc(6 * NC * H * sizeof(float));      // 3 MB
    float* Cf      = (float*)alloc(3 * NC * H * sizeof(float));
    float* Cs      = (float*)alloc(3 * NC * H * sizeof(float));
    int*   counts  = (int*)  alloc(NBKT * sizeof(int));
    int*   offs    = (int*)  alloc((NBKT + 1) * sizeof(int));
    int*   cur     = (int*)  alloc(NBKT * sizeof(int));
    int*   sorted  = (int*)  alloc(NE_TOT * sizeof(int));
    float* pbuf    = (float*)alloc((size_t)CHUNK * H * sizeof(float));  // 8.4 MB
    float* gfb     = (float*)alloc((size_t)CHUNK * H * sizeof(float));
    float* gsb     = (float*)alloc((size_t)CHUNK * H * sizeof(float));
    float* out     = (float*)d_out;

    // ---- CSR build + dst-side precompute ----
    zero_kernel<<<(6 * NC * H + 255) / 256, 256, 0, stream>>>(partial, counts);
    count_kernel<<<(NE_TOT + 255) / 256, 256, 0, stream>>>(e_ac, e_bc, e_mc, counts);
    scan_kernel<<<1, 1024, 0, stream>>>(counts, offs, cur);
    scatter_kernel<<<(NE_TOT + 255) / 256, 256, 0, stream>>>(e_ac, e_bc, e_mc, cur, sorted);
    dim3 cg(NC / 4, 3);
    cellpart_kernel<<<cg, 256, 0, stream>>>(x_cell, Wf, bf, Ws, bs, Cf, Cs);

    const size_t WHH = 2 * H * H;
    const float* WfB[3] = { Wf + 6 * WHH + 64 * H, Wf + 7 * WHH + 64 * H, Wf + 8 * WHH + 64 * H };
    const float* WsB[3] = { Ws + 6 * WHH + 64 * H, Ws + 7 * WHH + 64 * H, Ws + 8 * WHH + 64 * H };

    // ---- relation ac: atoms, 2 chunks of 32768 ----
    for (int c = 0; c < 2; ++c) {
        int b0 = c * CHUNK;
        proj_kernel<92><<<CHUNK / 4, 256, 0, stream>>>(x_atom + (size_t)b0 * 92, Wa, ba, pbuf, CHUNK);
        g_kernel<<<CHUNK / 32, 256, 0, stream>>>(pbuf, WfB[0], WsB[0], gfb, gsb);
        accum_kernel<<<1024, 256, 0, stream>>>(gfb, gsb, sorted, offs, Cf, Cs, partial, 0, b0, b0 + CHUNK);
    }
    // ---- relation bc: bonds, 4 chunks ----
    for (int c = 0; c < 4; ++c) {
        int b0 = c * CHUNK;
        proj_kernel<7><<<CHUNK / 4, 256, 0, stream>>>(x_bond + (size_t)b0 * 7, Wb, bb, pbuf, CHUNK);
        g_kernel<<<CHUNK / 32, 256, 0, stream>>>(pbuf, WfB[1], WsB[1], gfb, gsb);
        accum_kernel<<<1024, 256, 0, stream>>>(gfb, gsb, sorted, offs, Cf, Cs, partial, 1, b0, b0 + CHUNK);
    }
    // ---- relation mc: motifs, 1 chunk of 16384 ----
    {
        proj_kernel<35><<<NM / 4, 256, 0, stream>>>(x_motif, Wm, bm, pbuf, NM);
        g_kernel<<<NM / 32, 256, 0, stream>>>(pbuf, WfB[2], WsB[2], gfb, gsb);
        accum_kernel<<<1024, 256, 0, stream>>>(gfb, gsb, sorted, offs, Cf, Cs, partial, 2, 0, NM);
    }

    head_kernel<<<(NC + 255) / 256, 256, 0, stream>>>(partial, x_cell, Wp, bp, Wo, bo, out);
}

// Round 3
// 207.088 us; speedup vs baseline: 5.0765x; 2.5028x over previous
//
#include <hip/hip_runtime.h>
#include <hip/hip_fp16.h>

#define H 64
#define NA 65536
#define NB 131072
#define NM 16384
#define NC 2048
#define E_AC 65536
#define E_BC 131072
#define E_MC 16384
#define NE_TOT (E_AC + E_BC + E_MC)
#define NBKT (3 * NC)

__device__ __forceinline__ float sigmoidf_(float x) { return 1.0f / (1.0f + __expf(-x)); }
__device__ __forceinline__ float softplusf_(float x) {
    return fmaxf(x, 0.0f) + __logf(1.0f + __expf(-fabsf(x)));
}

// ---------------- CSR build ----------------
__global__ __launch_bounds__(256) void count_kernel(
    const int* __restrict__ ea, const int* __restrict__ eb, const int* __restrict__ em,
    int* __restrict__ counts)
{
    int i = blockIdx.x * 256 + threadIdx.x;
    int r, d;
    if (i < E_AC)                { r = 0; d = ea[E_AC + i]; }
    else if (i < E_AC + E_BC)    { r = 1; d = eb[E_BC + (i - E_AC)]; }
    else if (i < NE_TOT)         { r = 2; d = em[E_MC + (i - E_AC - E_BC)]; }
    else return;
    atomicAdd(&counts[r * NC + d], 1);
}

__global__ __launch_bounds__(1024) void scan_kernel(
    const int* __restrict__ cnt, int* __restrict__ off, int* __restrict__ cur)
{
    __shared__ int ps[1024];
    int t = threadIdx.x;
    int v[6], loc[6], s = 0;
    #pragma unroll
    for (int i = 0; i < 6; ++i) v[i] = cnt[t * 6 + i];
    #pragma unroll
    for (int i = 0; i < 6; ++i) { loc[i] = s; s += v[i]; }
    ps[t] = s;
    __syncthreads();
    for (int d = 1; d < 1024; d <<= 1) {
        int val = (t >= d) ? ps[t - d] : 0;
        __syncthreads();
        ps[t] += val;
        __syncthreads();
    }
    int base = (t > 0) ? ps[t - 1] : 0;
    #pragma unroll
    for (int i = 0; i < 6; ++i) { int o = base + loc[i]; off[t * 6 + i] = o; cur[t * 6 + i] = o; }
    if (t == 1023) off[NBKT] = ps[1023];
}

__global__ __launch_bounds__(256) void scatter_kernel(
    const int* __restrict__ ea, const int* __restrict__ eb, const int* __restrict__ em,
    int* __restrict__ cur, int* __restrict__ sorted)
{
    int i = blockIdx.x * 256 + threadIdx.x;
    int r, d, s;
    if (i < E_AC)                { r = 0; s = ea[i];               d = ea[E_AC + i]; }
    else if (i < E_AC + E_BC)    { int k = i - E_AC; r = 1; s = eb[k]; d = eb[E_BC + k]; }
    else if (i < NE_TOT)         { int k = i - E_AC - E_BC; r = 2; s = em[k]; d = em[E_MC + k]; }
    else return;
    int pos = atomicAdd(&cur[r * NC + d], 1);
    sorted[pos] = s;
}

// ---------------- dst-side precompute: Cf/Cs[r][2048][64] = x_cell @ W_top + bias ----
__global__ __launch_bounds__(256) void cellpart_kernel(
    const float* __restrict__ xc, const float* __restrict__ Wf, const float* __restrict__ bf,
    const float* __restrict__ Ws, const float* __restrict__ bs,
    float* __restrict__ Cf, float* __restrict__ Cs)
{
    int r = blockIdx.y;  // 0..2 -> relation 6+r
    const float* WfT = Wf + (size_t)(6 + r) * 2 * H * H;  // top half = rows 0..63
    const float* WsT = Ws + (size_t)(6 + r) * 2 * H * H;
    __shared__ float Wl[2][H * H];
    for (int i = threadIdx.x; i < H * H; i += 256) { Wl[0][i] = WfT[i]; Wl[1][i] = WsT[i]; }
    __syncthreads();
    int row = blockIdx.x * 4 + (threadIdx.x >> 6);
    int col = threadIdx.x & 63;
    const float* xr = xc + (size_t)row * H;
    float af = bf[(6 + r) * H + col], as = bs[(6 + r) * H + col];
    #pragma unroll
    for (int k = 0; k < H; ++k) {
        float xv = xr[k];
        af = fmaf(xv, Wl[0][k * H + col], af);
        as = fmaf(xv, Wl[1][k * H + col], as);
    }
    Cf[((size_t)r * NC + row) * H + col] = af;
    Cs[((size_t)r * NC + row) * H + col] = as;
}

// ---------------- fused src projection + bottom-half matmul ----------------
// p[row] = x[row,0:K] @ W + b ;  g[row][col] = half2( p@WfB , p@WsB )
template<int K>
__global__ __launch_bounds__(256) void projg_kernel(
    const float* __restrict__ x, const float* __restrict__ W, const float* __restrict__ b,
    const float* __restrict__ WfB, const float* __restrict__ WsB,
    __half2* __restrict__ g, int n)
{
    __shared__ float WL[K * H];     // proj weight
    __shared__ float xL[32 * K];    // 32 input rows
    __shared__ float pL[32 * H];    // projected rows
    int col = threadIdx.x & 63;
    int q = threadIdx.x >> 6;       // 4 lane-groups, 8 rows each
    int r0 = blockIdx.x * 32;

    float wf[64], ws[64];
    #pragma unroll
    for (int k = 0; k < 64; ++k) { wf[k] = WfB[k * H + col]; ws[k] = WsB[k * H + col]; }

    for (int i = threadIdx.x; i < K * H; i += 256) WL[i] = W[i];
    for (int i = threadIdx.x; i < 32 * K; i += 256) xL[i] = x[(size_t)r0 * K + i];
    __syncthreads();

    float bcol = b[col];
    for (int row = q * 8; row < q * 8 + 8; ++row) {
        // proj (wave-local: this wave computes all 64 cols of this row)
        float p = bcol;
        #pragma unroll
        for (int k = 0; k < K; ++k) p = fmaf(xL[row * K + k], WL[k * H + col], p);
        pL[row * H + col] = p;
        __builtin_amdgcn_s_waitcnt(0);  // drain LDS write before re-read (wave-local)
        // bottom-half matmul
        float af = 0.0f, as = 0.0f;
        #pragma unroll
        for (int kc = 0; kc < 16; ++kc) {
            float4 pv = *(const float4*)&pL[row * H + kc * 4];
            #pragma unroll
            for (int j = 0; j < 4; ++j) {
                float pe = (&pv.x)[j];
                af = fmaf(pe, wf[kc * 4 + j], af);
                as = fmaf(pe, ws[kc * 4 + j], as);
            }
        }
        g[(size_t)(r0 + row) * H + col] = __floats2half2_rn(af, as);
    }
}

// ---------------- edge accumulate: wave per (bucket, half), no atomics ----------------
__global__ __launch_bounds__(256) void accum_kernel(
    const __half2* __restrict__ g,
    const int* __restrict__ sorted, const int* __restrict__ off,
    const float* __restrict__ Cf, const float* __restrict__ Cs,
    float* __restrict__ partial, int r)
{
    int wid = blockIdx.x * 4 + (threadIdx.x >> 6);  // 0..4095
    int lane = threadIdx.x & 63;
    int d = wid >> 1, sub = wid & 1;
    int gb = r * NC + d;
    int j0 = off[gb], j1 = off[gb + 1];
    float cfv = Cf[(size_t)gb * H + lane];
    float csv = Cs[(size_t)gb * H + lane];
    float acc = 0.0f;
    int j = j0 + sub;
    for (; j + 6 < j1; j += 8) {
        int i0 = sorted[j], i1 = sorted[j + 2], i2 = sorted[j + 4], i3 = sorted[j + 6];
        float2 a0 = __half22float2(g[(size_t)i0 * H + lane]);
        float2 a1 = __half22float2(g[(size_t)i1 * H + lane]);
        float2 a2 = __half22float2(g[(size_t)i2 * H + lane]);
        float2 a3 = __half22float2(g[(size_t)i3 * H + lane]);
        acc += sigmoidf_(cfv + a0.x) * softplusf_(csv + a0.y);
        acc += sigmoidf_(cfv + a1.x) * softplusf_(csv + a1.y);
        acc += sigmoidf_(cfv + a2.x) * softplusf_(csv + a2.y);
        acc += sigmoidf_(cfv + a3.x) * softplusf_(csv + a3.y);
    }
    for (; j < j1; j += 2) {
        float2 a = __half22float2(g[(size_t)sorted[j] * H + lane]);
        acc += sigmoidf_(cfv + a.x) * softplusf_(csv + a.y);
    }
    partial[(((size_t)r * 2 + sub) * NC + d) * H + lane] = acc;  // direct store
}

// ---------------- head: wave per cell ----------------
__global__ __launch_bounds__(256) void head_kernel(
    const float* __restrict__ partial, const float* __restrict__ xc,
    const float* __restrict__ Wp, const float* __restrict__ bp,
    const float* __restrict__ Wo, const float* __restrict__ bo,
    float* __restrict__ out)
{
    __shared__ float vL[4][H];
    int lane = threadIdx.x & 63;
    int w = threadIdx.x >> 6;
    int c = blockIdx.x * 4 + w;
    float a = 3.0f * xc[(size_t)c * H + lane];
    #pragma unroll
    for (int t = 0; t < 6; ++t) a += partial[((size_t)t * NC + c) * H + lane];
    vL[w][lane] = fmaxf(a, 0.0f);
    __syncthreads();
    // lane = output column j of Wp
    float aj = bp[lane];
    #pragma unroll
    for (int k = 0; k < H; ++k) aj = fmaf(vL[w][k], Wp[k * H + lane], aj);
    float contrib = softplusf_(aj) * Wo[lane];
    #pragma unroll
    for (int o = 32; o > 0; o >>= 1) contrib += __shfl_down(contrib, o, 64);
    if (lane == 0) out[c] = contrib + bo[0];
}

extern "C" void kernel_launch(void* const* d_in, const int* in_sizes, int n_in,
                              void* d_out, int out_size, void* d_ws, size_t ws_size,
                              hipStream_t stream)
{
    const float* x_atom  = (const float*)d_in[0];
    const float* x_bond  = (const float*)d_in[1];
    const float* x_motif = (const float*)d_in[2];
    const float* x_cell  = (const float*)d_in[3];
    const float* Wa = (const float*)d_in[4];
    const float* ba = (const float*)d_in[5];
    const float* Wb = (const float*)d_in[6];
    const float* bb = (const float*)d_in[7];
    const float* Wm = (const float*)d_in[8];
    const float* bm = (const float*)d_in[9];
    const float* Wf = (const float*)d_in[10];
    const float* bf = (const float*)d_in[11];
    const float* Ws = (const float*)d_in[12];
    const float* bs = (const float*)d_in[13];
    const float* Wp = (const float*)d_in[14];
    const float* bp = (const float*)d_in[15];
    const float* Wo = (const float*)d_in[16];
    const float* bo = (const float*)d_in[17];
    const int* e_ac = (const int*)d_in[24];
    const int* e_bc = (const int*)d_in[25];
    const int* e_mc = (const int*)d_in[26];

    // ---- workspace layout (256B-aligned), ~40.6 MB (R1 proved 55 MB ok) ----
    char* base = (char*)d_ws;
    size_t o = 0;
    auto alloc = [&](size_t bytes) { char* r = base + o; o = (o + bytes + 255) & ~(size_t)255; return r; };
    float*   Cf      = (float*)  alloc(3 * NC * H * sizeof(float));
    float*   Cs      = (float*)  alloc(3 * NC * H * sizeof(float));
    float*   partial = (float*)  alloc(6 * NC * H * sizeof(float));
    int*     counts  = (int*)    alloc(NBKT * sizeof(int));
    int*     offs    = (int*)    alloc((NBKT + 1) * sizeof(int));
    int*     cur     = (int*)    alloc(NBKT * sizeof(int));
    int*     sorted  = (int*)    alloc(NE_TOT * sizeof(int));
    __half2* gbuf    = (__half2*)alloc((size_t)NB * H * sizeof(__half2));  // 33.6 MB, reused
    float*   out     = (float*)d_out;

    // ---- CSR build ----
    hipMemsetAsync(counts, 0, NBKT * sizeof(int), stream);
    count_kernel<<<(NE_TOT + 255) / 256, 256, 0, stream>>>(e_ac, e_bc, e_mc, counts);
    scan_kernel<<<1, 1024, 0, stream>>>(counts, offs, cur);
    scatter_kernel<<<(NE_TOT + 255) / 256, 256, 0, stream>>>(e_ac, e_bc, e_mc, cur, sorted);

    // ---- dst-side precompute ----
    dim3 cg(NC / 4, 3);
    cellpart_kernel<<<cg, 256, 0, stream>>>(x_cell, Wf, bf, Ws, bs, Cf, Cs);

    const size_t WHH = 2 * H * H;
    const float* WfB[3] = { Wf + 6 * WHH + (size_t)H * H, Wf + 7 * WHH + (size_t)H * H, Wf + 8 * WHH + (size_t)H * H };
    const float* WsB[3] = { Ws + 6 * WHH + (size_t)H * H, Ws + 7 * WHH + (size_t)H * H, Ws + 8 * WHH + (size_t)H * H };

    // ---- per relation: full-array projg + accum (G buffer reused) ----
    projg_kernel<92><<<NA / 32, 256, 0, stream>>>(x_atom, Wa, ba, WfB[0], WsB[0], gbuf, NA);
    accum_kernel<<<NC * 2 / 4, 256, 0, stream>>>(gbuf, sorted, offs, Cf, Cs, partial, 0);

    projg_kernel<7><<<NB / 32, 256, 0, stream>>>(x_bond, Wb, bb, WfB[1], WsB[1], gbuf, NB);
    accum_kernel<<<NC * 2 / 4, 256, 0, stream>>>(gbuf, sorted, offs, Cf, Cs, partial, 1);

    projg_kernel<35><<<NM / 32, 256, 0, stream>>>(x_motif, Wm, bm, WfB[2], WsB[2], gbuf, NM);
    accum_kernel<<<NC * 2 / 4, 256, 0, stream>>>(gbuf, sorted, offs, Cf, Cs, partial, 2);

    // ---- head ----
    head_kernel<<<NC / 4, 256, 0, stream>>>(partial, x_cell, Wp, bp, Wo, bo, out);
}

// Round 4
// 171.243 us; speedup vs baseline: 6.1391x; 1.2093x over previous
//
#include <hip/hip_runtime.h>
#include <hip/hip_fp16.h>

#define H 64
#define NA 65536
#define NB 131072
#define NM 16384
#define NC 2048
#define E_AC 65536
#define E_BC 131072
#define E_MC 16384
#define NE_TOT (E_AC + E_BC + E_MC)
#define NBKT (3 * NC)

__device__ __forceinline__ float sigmoidf_(float x) { return 1.0f / (1.0f + __expf(-x)); }
__device__ __forceinline__ float softplusf_(float x) {
    return fmaxf(x, 0.0f) + __logf(1.0f + __expf(-fabsf(x)));
}

// ---------------- CSR build ----------------
__global__ __launch_bounds__(256) void count_kernel(
    const int* __restrict__ ea, const int* __restrict__ eb, const int* __restrict__ em,
    int* __restrict__ counts)
{
    int i = blockIdx.x * 256 + threadIdx.x;
    int r, d;
    if (i < E_AC)                { r = 0; d = ea[E_AC + i]; }
    else if (i < E_AC + E_BC)    { r = 1; d = eb[E_BC + (i - E_AC)]; }
    else if (i < NE_TOT)         { r = 2; d = em[E_MC + (i - E_AC - E_BC)]; }
    else return;
    atomicAdd(&counts[r * NC + d], 1);
}

__global__ __launch_bounds__(1024) void scan_kernel(
    const int* __restrict__ cnt, int* __restrict__ off, int* __restrict__ cur)
{
    __shared__ int ps[1024];
    int t = threadIdx.x;
    int v[6], loc[6], s = 0;
    #pragma unroll
    for (int i = 0; i < 6; ++i) v[i] = cnt[t * 6 + i];
    #pragma unroll
    for (int i = 0; i < 6; ++i) { loc[i] = s; s += v[i]; }
    ps[t] = s;
    __syncthreads();
    for (int d = 1; d < 1024; d <<= 1) {
        int val = (t >= d) ? ps[t - d] : 0;
        __syncthreads();
        ps[t] += val;
        __syncthreads();
    }
    int base = (t > 0) ? ps[t - 1] : 0;
    #pragma unroll
    for (int i = 0; i < 6; ++i) { int o = base + loc[i]; off[t * 6 + i] = o; cur[t * 6 + i] = o; }
    if (t == 1023) off[NBKT] = ps[1023];
}

__global__ __launch_bounds__(256) void scatter_kernel(
    const int* __restrict__ ea, const int* __restrict__ eb, const int* __restrict__ em,
    int* __restrict__ cur, int* __restrict__ sorted)
{
    int i = blockIdx.x * 256 + threadIdx.x;
    int r, d, s;
    if (i < E_AC)                { r = 0; s = ea[i];               d = ea[E_AC + i]; }
    else if (i < E_AC + E_BC)    { int k = i - E_AC; r = 1; s = eb[k]; d = eb[E_BC + k]; }
    else if (i < NE_TOT)         { int k = i - E_AC - E_BC; r = 2; s = em[k]; d = em[E_MC + k]; }
    else return;
    int pos = atomicAdd(&cur[r * NC + d], 1);
    sorted[pos] = s;
}

// ---------------- dst-side precompute: Cf/Cs[r][2048][64] = x_cell @ W_top + bias ----
__global__ __launch_bounds__(256) void cellpart_kernel(
    const float* __restrict__ xc, const float* __restrict__ Wf, const float* __restrict__ bf,
    const float* __restrict__ Ws, const float* __restrict__ bs,
    float* __restrict__ Cf, float* __restrict__ Cs)
{
    int r = blockIdx.y;  // 0..2 -> relation 6+r
    const float* WfT = Wf + (size_t)(6 + r) * 2 * H * H;  // top half = rows 0..63
    const float* WsT = Ws + (size_t)(6 + r) * 2 * H * H;
    __shared__ float Wl[2][H * H];
    for (int i = threadIdx.x; i < H * H; i += 256) { Wl[0][i] = WfT[i]; Wl[1][i] = WsT[i]; }
    __syncthreads();
    int row = blockIdx.x * 4 + (threadIdx.x >> 6);
    int col = threadIdx.x & 63;
    const float* xr = xc + (size_t)row * H;
    float af = bf[(6 + r) * H + col], as = bs[(6 + r) * H + col];
    #pragma unroll
    for (int k = 0; k < H; ++k) {
        float xv = xr[k];
        af = fmaf(xv, Wl[0][k * H + col], af);
        as = fmaf(xv, Wl[1][k * H + col], as);
    }
    Cf[((size_t)r * NC + row) * H + col] = af;
    Cs[((size_t)r * NC + row) * H + col] = as;
}

// ---------------- composite weight: Wc[k][c] = half2( Wsrc[k,:]@WfB[:,c], Wsrc[k,:]@WsB[:,c] )
// row K (last) is the composite bias: bsrc @ WfB / WsB
__global__ __launch_bounds__(256) void wcomp_kernel(
    const float* __restrict__ Wsrc, const float* __restrict__ bsrc, int K,
    const float* __restrict__ Wf, const float* __restrict__ Ws, int rabs,
    __half2* __restrict__ Wc)
{
    const float* WfB = Wf + (size_t)rabs * 2 * H * H + (size_t)H * H;
    const float* WsB = Ws + (size_t)rabs * 2 * H * H + (size_t)H * H;
    int col = threadIdx.x & 63;
    int krow = blockIdx.x * 4 + (threadIdx.x >> 6);
    if (krow > K) return;
    const float* a = (krow < K) ? (Wsrc + (size_t)krow * H) : bsrc;
    float f = 0.0f, s = 0.0f;
    for (int j = 0; j < H; ++j) {
        float av = a[j];
        f = fmaf(av, WfB[j * H + col], f);
        s = fmaf(av, WsB[j * H + col], s);
    }
    Wc[(size_t)krow * H + col] = __floats2half2_rn(f, s);
}

// ---------------- G build: g[n][col] = half2( x[n,:]@WcF + bF , x[n,:]@WcS + bS ) ------
template<int K>
__global__ __launch_bounds__(256) void gcomp_kernel(
    const float* __restrict__ x, const __half2* __restrict__ Wc,
    __half2* __restrict__ g)
{
    constexpr int KP = (K + 3) & ~3;
    __shared__ float xL[32 * KP];
    int col = threadIdx.x & 63;
    int q = threadIdx.x >> 6;
    int r0 = blockIdx.x * 32;

    __half2 wc[KP];
    #pragma unroll
    for (int k = 0; k < KP; ++k)
        wc[k] = (k < K) ? Wc[k * H + col] : __floats2half2_rn(0.0f, 0.0f);
    __half2 gb = Wc[(size_t)K * H + col];

    for (int i = threadIdx.x; i < 32 * KP; i += 256) {
        int r = i / KP, k = i - r * KP;
        xL[i] = (k < K) ? x[(size_t)(r0 + r) * K + k] : 0.0f;
    }
    __syncthreads();

    #pragma unroll
    for (int rr = 0; rr < 8; ++rr) {
        int row = q * 8 + rr;
        float accf = __low2float(gb), accs = __high2float(gb);
        #pragma unroll
        for (int kc = 0; kc < KP / 4; ++kc) {
            float4 xv = *(const float4*)&xL[row * KP + kc * 4];
            #pragma unroll
            for (int j = 0; j < 4; ++j) {
                float xe = (&xv.x)[j];
                __half2 w = wc[kc * 4 + j];
                accf = fmaf(xe, __low2float(w), accf);
                accs = fmaf(xe, __high2float(w), accs);
            }
        }
        g[(size_t)(r0 + row) * H + col] = __floats2half2_rn(accf, accs);
    }
}

// ---------------- edge accumulate: wave per (bucket, quarter), no atomics --------------
__global__ __launch_bounds__(256) void accum_kernel(
    const __half2* __restrict__ g,
    const int* __restrict__ sorted, const int* __restrict__ off,
    const float* __restrict__ Cf, const float* __restrict__ Cs,
    float* __restrict__ partial, int r)
{
    int wid = blockIdx.x * 4 + (threadIdx.x >> 6);  // 0..8191
    int lane = threadIdx.x & 63;
    int d = wid >> 2, sub = wid & 3;
    int gb = r * NC + d;
    int j0 = off[gb], j1 = off[gb + 1];
    float cfv = Cf[(size_t)gb * H + lane];
    float csv = Cs[(size_t)gb * H + lane];
    float acc = 0.0f;
    int j = j0 + sub;
    for (; j + 12 < j1; j += 16) {
        int i0 = sorted[j], i1 = sorted[j + 4], i2 = sorted[j + 8], i3 = sorted[j + 12];
        float2 a0 = __half22float2(g[(size_t)i0 * H + lane]);
        float2 a1 = __half22float2(g[(size_t)i1 * H + lane]);
        float2 a2 = __half22float2(g[(size_t)i2 * H + lane]);
        float2 a3 = __half22float2(g[(size_t)i3 * H + lane]);
        acc += sigmoidf_(cfv + a0.x) * softplusf_(csv + a0.y);
        acc += sigmoidf_(cfv + a1.x) * softplusf_(csv + a1.y);
        acc += sigmoidf_(cfv + a2.x) * softplusf_(csv + a2.y);
        acc += sigmoidf_(cfv + a3.x) * softplusf_(csv + a3.y);
    }
    for (; j < j1; j += 4) {
        float2 a = __half22float2(g[(size_t)sorted[j] * H + lane]);
        acc += sigmoidf_(cfv + a.x) * softplusf_(csv + a.y);
    }
    partial[(((size_t)r * 4 + sub) * NC + d) * H + lane] = acc;
}

// ---------------- head: wave per cell ----------------
__global__ __launch_bounds__(256) void head_kernel(
    const float* __restrict__ partial, const float* __restrict__ xc,
    const float* __restrict__ Wp, const float* __restrict__ bp,
    const float* __restrict__ Wo, const float* __restrict__ bo,
    float* __restrict__ out)
{
    __shared__ float vL[4][H];
    int lane = threadIdx.x & 63;
    int w = threadIdx.x >> 6;
    int c = blockIdx.x * 4 + w;
    float a = 3.0f * xc[(size_t)c * H + lane];
    #pragma unroll
    for (int t = 0; t < 12; ++t) a += partial[((size_t)t * NC + c) * H + lane];
    vL[w][lane] = fmaxf(a, 0.0f);
    __syncthreads();
    float aj = bp[lane];
    #pragma unroll
    for (int k = 0; k < H; ++k) aj = fmaf(vL[w][k], Wp[k * H + lane], aj);
    float contrib = softplusf_(aj) * Wo[lane];
    #pragma unroll
    for (int o = 32; o > 0; o >>= 1) contrib += __shfl_down(contrib, o, 64);
    if (lane == 0) out[c] = contrib + bo[0];
}

extern "C" void kernel_launch(void* const* d_in, const int* in_sizes, int n_in,
                              void* d_out, int out_size, void* d_ws, size_t ws_size,
                              hipStream_t stream)
{
    const float* x_atom  = (const float*)d_in[0];
    const float* x_bond  = (const float*)d_in[1];
    const float* x_motif = (const float*)d_in[2];
    const float* x_cell  = (const float*)d_in[3];
    const float* Wa = (const float*)d_in[4];
    const float* ba = (const float*)d_in[5];
    const float* Wb = (const float*)d_in[6];
    const float* bb = (const float*)d_in[7];
    const float* Wm = (const float*)d_in[8];
    const float* bm = (const float*)d_in[9];
    const float* Wf = (const float*)d_in[10];
    const float* bf = (const float*)d_in[11];
    const float* Ws = (const float*)d_in[12];
    const float* bs = (const float*)d_in[13];
    const float* Wp = (const float*)d_in[14];
    const float* bp = (const float*)d_in[15];
    const float* Wo = (const float*)d_in[16];
    const float* bo = (const float*)d_in[17];
    const int* e_ac = (const int*)d_in[24];
    const int* e_bc = (const int*)d_in[25];
    const int* e_mc = (const int*)d_in[26];

    // ---- workspace layout (256B-aligned), ~43.5 MB ----
    char* base = (char*)d_ws;
    size_t o = 0;
    auto alloc = [&](size_t bytes) { char* r = base + o; o = (o + bytes + 255) & ~(size_t)255; return r; };
    float*   Cf      = (float*)  alloc(3 * NC * H * sizeof(float));
    float*   Cs      = (float*)  alloc(3 * NC * H * sizeof(float));
    float*   partial = (float*)  alloc(12 * NC * H * sizeof(float));   // 6 MB
    int*     counts  = (int*)    alloc(NBKT * sizeof(int));
    int*     offs    = (int*)    alloc((NBKT + 1) * sizeof(int));
    int*     cur     = (int*)    alloc(NBKT * sizeof(int));
    int*     sorted  = (int*)    alloc(NE_TOT * sizeof(int));
    __half2* WcA     = (__half2*)alloc(93 * H * sizeof(__half2));
    __half2* WcB     = (__half2*)alloc(8  * H * sizeof(__half2));
    __half2* WcM     = (__half2*)alloc(36 * H * sizeof(__half2));
    __half2* gbuf    = (__half2*)alloc((size_t)NB * H * sizeof(__half2));  // 33.6 MB, reused
    float*   out     = (float*)d_out;

    // ---- CSR build ----
    hipMemsetAsync(counts, 0, NBKT * sizeof(int), stream);
    count_kernel<<<(NE_TOT + 255) / 256, 256, 0, stream>>>(e_ac, e_bc, e_mc, counts);
    scan_kernel<<<1, 1024, 0, stream>>>(counts, offs, cur);
    scatter_kernel<<<(NE_TOT + 255) / 256, 256, 0, stream>>>(e_ac, e_bc, e_mc, cur, sorted);

    // ---- dst-side + composite weights ----
    dim3 cg(NC / 4, 3);
    cellpart_kernel<<<cg, 256, 0, stream>>>(x_cell, Wf, bf, Ws, bs, Cf, Cs);
    wcomp_kernel<<<(92 + 1 + 3) / 4, 256, 0, stream>>>(Wa, ba, 92, Wf, Ws, 6, WcA);
    wcomp_kernel<<<(7  + 1 + 3) / 4, 256, 0, stream>>>(Wb, bb, 7,  Wf, Ws, 7, WcB);
    wcomp_kernel<<<(35 + 1 + 3) / 4, 256, 0, stream>>>(Wm, bm, 35, Wf, Ws, 8, WcM);

    // ---- per relation: composite G + accum (G buffer reused) ----
    gcomp_kernel<92><<<NA / 32, 256, 0, stream>>>(x_atom, WcA, gbuf);
    accum_kernel<<<NC * 4 / 4, 256, 0, stream>>>(gbuf, sorted, offs, Cf, Cs, partial, 0);

    gcomp_kernel<7><<<NB / 32, 256, 0, stream>>>(x_bond, WcB, gbuf);
    accum_kernel<<<NC * 4 / 4, 256, 0, stream>>>(gbuf, sorted, offs, Cf, Cs, partial, 1);

    gcomp_kernel<35><<<NM / 32, 256, 0, stream>>>(x_motif, WcM, gbuf);
    accum_kernel<<<NC * 4 / 4, 256, 0, stream>>>(gbuf, sorted, offs, Cf, Cs, partial, 2);

    // ---- head ----
    head_kernel<<<NC / 4, 256, 0, stream>>>(partial, x_cell, Wp, bp, Wo, bo, out);
}

// Round 5
// 128.350 us; speedup vs baseline: 8.1907x; 1.3342x over previous
//
#include <hip/hip_runtime.h>
#include <hip/hip_fp16.h>

#define H 64
#define NA 65536
#define NB 131072
#define NM 16384
#define NC 2048
#define E_AC 65536
#define E_BC 131072
#define E_MC 16384
#define NE_TOT (E_AC + E_BC + E_MC)
#define NBKT (3 * NC)

typedef __attribute__((ext_vector_type(8))) short bf16x8;
typedef __attribute__((ext_vector_type(4))) float f32x4;

__device__ __forceinline__ float sigmoidf_(float x) { return 1.0f / (1.0f + __expf(-x)); }
__device__ __forceinline__ float softplusf_(float x) {
    return fmaxf(x, 0.0f) + __logf(1.0f + __expf(-fabsf(x)));
}
__device__ __forceinline__ short bf16_of(float f) {
    union { float f; unsigned u; } v; v.f = f;
    unsigned r = (v.u + 0x7fff + ((v.u >> 16) & 1)) >> 16;  // RNE
    return (short)r;
}

// ---------------- CSR build ----------------
__global__ __launch_bounds__(256) void count_kernel(
    const int* __restrict__ ea, const int* __restrict__ eb, const int* __restrict__ em,
    int* __restrict__ counts)
{
    int i = blockIdx.x * 256 + threadIdx.x;
    int r, d;
    if (i < E_AC)                { r = 0; d = ea[E_AC + i]; }
    else if (i < E_AC + E_BC)    { r = 1; d = eb[E_BC + (i - E_AC)]; }
    else if (i < NE_TOT)         { r = 2; d = em[E_MC + (i - E_AC - E_BC)]; }
    else return;
    atomicAdd(&counts[r * NC + d], 1);
}

__global__ __launch_bounds__(1024) void scan_kernel(
    const int* __restrict__ cnt, int* __restrict__ off, int* __restrict__ cur)
{
    __shared__ int ps[1024];
    int t = threadIdx.x;
    int v[6], loc[6], s = 0;
    #pragma unroll
    for (int i = 0; i < 6; ++i) v[i] = cnt[t * 6 + i];
    #pragma unroll
    for (int i = 0; i < 6; ++i) { loc[i] = s; s += v[i]; }
    ps[t] = s;
    __syncthreads();
    for (int d = 1; d < 1024; d <<= 1) {
        int val = (t >= d) ? ps[t - d] : 0;
        __syncthreads();
        ps[t] += val;
        __syncthreads();
    }
    int base = (t > 0) ? ps[t - 1] : 0;
    #pragma unroll
    for (int i = 0; i < 6; ++i) { int o = base + loc[i]; off[t * 6 + i] = o; cur[t * 6 + i] = o; }
    if (t == 1023) off[NBKT] = ps[1023];
}

__global__ __launch_bounds__(256) void scatter_kernel(
    const int* __restrict__ ea, const int* __restrict__ eb, const int* __restrict__ em,
    int* __restrict__ cur, int* __restrict__ sorted)
{
    int i = blockIdx.x * 256 + threadIdx.x;
    int r, d, s;
    if (i < E_AC)                { r = 0; s = ea[i];               d = ea[E_AC + i]; }
    else if (i < E_AC + E_BC)    { int k = i - E_AC; r = 1; s = eb[k]; d = eb[E_BC + k]; }
    else if (i < NE_TOT)         { int k = i - E_AC - E_BC; r = 2; s = em[k]; d = em[E_MC + k]; }
    else return;
    int pos = atomicAdd(&cur[r * NC + d], 1);
    sorted[pos] = s;
}

// ---------------- dst-side precompute: Cf/Cs[r][2048][64] = x_cell @ W_top + bias ----
__global__ __launch_bounds__(256) void cellpart_kernel(
    const float* __restrict__ xc, const float* __restrict__ Wf, const float* __restrict__ bf,
    const float* __restrict__ Ws, const float* __restrict__ bs,
    float* __restrict__ Cf, float* __restrict__ Cs)
{
    int r = blockIdx.y;
    const float* WfT = Wf + (size_t)(6 + r) * 2 * H * H;
    const float* WsT = Ws + (size_t)(6 + r) * 2 * H * H;
    __shared__ float Wl[2][H * H];
    for (int i = threadIdx.x; i < H * H; i += 256) { Wl[0][i] = WfT[i]; Wl[1][i] = WsT[i]; }
    __syncthreads();
    int row = blockIdx.x * 4 + (threadIdx.x >> 6);
    int col = threadIdx.x & 63;
    const float* xr = xc + (size_t)row * H;
    float af = bf[(6 + r) * H + col], as = bs[(6 + r) * H + col];
    #pragma unroll
    for (int k = 0; k < H; ++k) {
        float xv = xr[k];
        af = fmaf(xv, Wl[0][k * H + col], af);
        as = fmaf(xv, Wl[1][k * H + col], as);
    }
    Cf[((size_t)r * NC + row) * H + col] = af;
    Cs[((size_t)r * NC + row) * H + col] = as;
}

// ---------------- composite weights packed into MFMA B-fragment order --------------
// Wc[k][col] (col<64: f-part, col>=64: s-part), k zero-padded to KP=S*32.
// Pack position: tile t=col>>4, lane l=((k>>3)&3)*16 + (col&15), elem e=k&7, step s=k>>5
// flat = ((t*S + s)*64 + l)*8 + e.   bias[rel*128 + col] = bsrc @ W_bot.
__global__ __launch_bounds__(256) void wcomp_pack_kernel(
    const float* __restrict__ Wa, const float* __restrict__ ba,
    const float* __restrict__ Wb, const float* __restrict__ bb,
    const float* __restrict__ Wm, const float* __restrict__ bm,
    const float* __restrict__ Wf, const float* __restrict__ Ws,
    short* __restrict__ wpA, short* __restrict__ wpB, short* __restrict__ wpM,
    float* __restrict__ bias)
{
    int rel = blockIdx.y;
    int K, S; const float* Wsrc; const float* bsrc; short* wp;
    if (rel == 0)      { K = 92; S = 3; Wsrc = Wa; bsrc = ba; wp = wpA; }
    else if (rel == 1) { K = 7;  S = 1; Wsrc = Wb; bsrc = bb; wp = wpB; }
    else               { K = 35; S = 2; Wsrc = Wm; bsrc = bm; wp = wpM; }
    const float* WfB = Wf + (size_t)(6 + rel) * 2 * H * H + (size_t)H * H;
    const float* WsB = Ws + (size_t)(6 + rel) * 2 * H * H + (size_t)H * H;
    int KP = S * 32;
    int idx = blockIdx.x * 256 + threadIdx.x;
    if (idx < KP * 128) {
        int k = idx >> 7, col = idx & 127;
        int c = col & 63;
        const float* Wcol = (col < 64) ? WfB : WsB;
        float v = 0.0f;
        if (k < K) {
            const float* a = Wsrc + (size_t)k * H;
            for (int j = 0; j < H; ++j) v = fmaf(a[j], Wcol[j * H + c], v);
        }
        int t = col >> 4, lo = col & 15, s = k >> 5, q = (k >> 3) & 3, e = k & 7;
        wp[(size_t)(((t * S + s) * 64) + q * 16 + lo) * 8 + e] = bf16_of(v);
    } else if (idx < KP * 128 + 128) {
        int col = idx - KP * 128;
        int c = col & 63;
        const float* Wcol = (col < 64) ? WfB : WsB;
        float v = 0.0f;
        for (int j = 0; j < H; ++j) v = fmaf(bsrc[j], Wcol[j * H + c], v);
        bias[rel * 128 + col] = v;
    }
}

// ---------------- MFMA G build: one wave = 16 rows x 128 cols --------------
// D = A(x rows, bf16) * B(packed Wc). A-frag: row=lane&15, k=(lane>>4)*8+e.
// D: col=lane&15, row=(lane>>4)*4+reg  [m89-verified]. g[row][c]=half2(f,s).
template<int K, int S>
__global__ __launch_bounds__(256) void gmfma_kernel(
    const float* __restrict__ x, const short* __restrict__ wp,
    const float* __restrict__ bias, __half2* __restrict__ g)
{
    int l = threadIdx.x & 63;
    int wv = threadIdx.x >> 6;
    int r0 = (blockIdx.x * 4 + wv) * 16;
    int lrow = l & 15, q = l >> 4;

    bf16x8 bfrag[8][S];
    #pragma unroll
    for (int t = 0; t < 8; ++t)
        #pragma unroll
        for (int s = 0; s < S; ++s)
            bfrag[t][s] = *(const bf16x8*)(wp + (size_t)((t * S + s) * 64 + l) * 8);

    float bF[4], bS[4];
    #pragma unroll
    for (int t = 0; t < 4; ++t) {
        bF[t] = bias[t * 16 + lrow];
        bS[t] = bias[64 + t * 16 + lrow];
    }

    f32x4 acc[8];
    #pragma unroll
    for (int t = 0; t < 8; ++t) acc[t] = (f32x4){0.f, 0.f, 0.f, 0.f};

    const float* xr = x + (size_t)(r0 + lrow) * K;
    #pragma unroll
    for (int s = 0; s < S; ++s) {
        int kb = s * 32 + q * 8;
        bf16x8 afrag;
        #pragma unroll
        for (int e = 0; e < 8; ++e) {
            float xv = 0.0f;
            if (kb + e < K) xv = xr[kb + e];   // predicated: no NaN into MFMA
            afrag[e] = bf16_of(xv);
        }
        #pragma unroll
        for (int t = 0; t < 8; ++t)
            acc[t] = __builtin_amdgcn_mfma_f32_16x16x32_bf16(afrag, bfrag[t][s], acc[t], 0, 0, 0);
    }

    #pragma unroll
    for (int t = 0; t < 4; ++t)
        #pragma unroll
        for (int r = 0; r < 4; ++r) {
            float fv = acc[t][r] + bF[t];
            float sv = acc[t + 4][r] + bS[t];
            g[(size_t)(r0 + q * 4 + r) * H + t * 16 + lrow] = __floats2half2_rn(fv, sv);
        }
}

// ---------------- edge accumulate: wave per (bucket, quarter), no atomics --------------
__global__ __launch_bounds__(256) void accum_kernel(
    const __half2* __restrict__ g,
    const int* __restrict__ sorted, const int* __restrict__ off,
    const float* __restrict__ Cf, const float* __restrict__ Cs,
    float* __restrict__ partial, int r)
{
    int wid = blockIdx.x * 4 + (threadIdx.x >> 6);
    int lane = threadIdx.x & 63;
    int d = wid >> 2, sub = wid & 3;
    int gb = r * NC + d;
    int j0 = off[gb], j1 = off[gb + 1];
    float cfv = Cf[(size_t)gb * H + lane];
    float csv = Cs[(size_t)gb * H + lane];
    float acc = 0.0f;
    int j = j0 + sub;
    for (; j + 12 < j1; j += 16) {
        int i0 = sorted[j], i1 = sorted[j + 4], i2 = sorted[j + 8], i3 = sorted[j + 12];
        float2 a0 = __half22float2(g[(size_t)i0 * H + lane]);
        float2 a1 = __half22float2(g[(size_t)i1 * H + lane]);
        float2 a2 = __half22float2(g[(size_t)i2 * H + lane]);
        float2 a3 = __half22float2(g[(size_t)i3 * H + lane]);
        acc += sigmoidf_(cfv + a0.x) * softplusf_(csv + a0.y);
        acc += sigmoidf_(cfv + a1.x) * softplusf_(csv + a1.y);
        acc += sigmoidf_(cfv + a2.x) * softplusf_(csv + a2.y);
        acc += sigmoidf_(cfv + a3.x) * softplusf_(csv + a3.y);
    }
    for (; j < j1; j += 4) {
        float2 a = __half22float2(g[(size_t)sorted[j] * H + lane]);
        acc += sigmoidf_(cfv + a.x) * softplusf_(csv + a.y);
    }
    partial[(((size_t)r * 4 + sub) * NC + d) * H + lane] = acc;
}

// ---------------- head: wave per cell ----------------
__global__ __launch_bounds__(256) void head_kernel(
    const float* __restrict__ partial, const float* __restrict__ xc,
    const float* __restrict__ Wp, const float* __restrict__ bp,
    const float* __restrict__ Wo, const float* __restrict__ bo,
    float* __restrict__ out)
{
    __shared__ float vL[4][H];
    int lane = threadIdx.x & 63;
    int w = threadIdx.x >> 6;
    int c = blockIdx.x * 4 + w;
    float a = 3.0f * xc[(size_t)c * H + lane];
    #pragma unroll
    for (int t = 0; t < 12; ++t) a += partial[((size_t)t * NC + c) * H + lane];
    vL[w][lane] = fmaxf(a, 0.0f);
    __syncthreads();
    float aj = bp[lane];
    #pragma unroll
    for (int k = 0; k < H; ++k) aj = fmaf(vL[w][k], Wp[k * H + lane], aj);
    float contrib = softplusf_(aj) * Wo[lane];
    #pragma unroll
    for (int o = 32; o > 0; o >>= 1) contrib += __shfl_down(contrib, o, 64);
    if (lane == 0) out[c] = contrib + bo[0];
}

extern "C" void kernel_launch(void* const* d_in, const int* in_sizes, int n_in,
                              void* d_out, int out_size, void* d_ws, size_t ws_size,
                              hipStream_t stream)
{
    const float* x_atom  = (const float*)d_in[0];
    const float* x_bond  = (const float*)d_in[1];
    const float* x_motif = (const float*)d_in[2];
    const float* x_cell  = (const float*)d_in[3];
    const float* Wa = (const float*)d_in[4];
    const float* ba = (const float*)d_in[5];
    const float* Wb = (const float*)d_in[6];
    const float* bb = (const float*)d_in[7];
    const float* Wm = (const float*)d_in[8];
    const float* bm = (const float*)d_in[9];
    const float* Wf = (const float*)d_in[10];
    const float* bf = (const float*)d_in[11];
    const float* Ws = (const float*)d_in[12];
    const float* bs = (const float*)d_in[13];
    const float* Wp = (const float*)d_in[14];
    const float* bp = (const float*)d_in[15];
    const float* Wo = (const float*)d_in[16];
    const float* bo = (const float*)d_in[17];
    const int* e_ac = (const int*)d_in[24];
    const int* e_bc = (const int*)d_in[25];
    const int* e_mc = (const int*)d_in[26];

    // ---- workspace layout (256B-aligned), ~46 MB ----
    char* base = (char*)d_ws;
    size_t o = 0;
    auto alloc = [&](size_t bytes) { char* r = base + o; o = (o + bytes + 255) & ~(size_t)255; return r; };
    float*   Cf      = (float*)  alloc(3 * NC * H * sizeof(float));
    float*   Cs      = (float*)  alloc(3 * NC * H * sizeof(float));
    float*   partial = (float*)  alloc(12 * NC * H * sizeof(float));
    int*     counts  = (int*)    alloc(NBKT * sizeof(int));
    int*     offs    = (int*)    alloc((NBKT + 1) * sizeof(int));
    int*     cur     = (int*)    alloc(NBKT * sizeof(int));
    int*     sorted  = (int*)    alloc(NE_TOT * sizeof(int));
    short*   wpA     = (short*)  alloc(8 * 3 * 64 * 8 * sizeof(short));
    short*   wpB     = (short*)  alloc(8 * 1 * 64 * 8 * sizeof(short));
    short*   wpM     = (short*)  alloc(8 * 2 * 64 * 8 * sizeof(short));
    float*   bias    = (float*)  alloc(3 * 128 * sizeof(float));
    __half2* gbuf    = (__half2*)alloc((size_t)NB * H * sizeof(__half2));  // 33.6 MB, reused
    float*   out     = (float*)d_out;

    // ---- CSR build ----
    hipMemsetAsync(counts, 0, NBKT * sizeof(int), stream);
    count_kernel<<<(NE_TOT + 255) / 256, 256, 0, stream>>>(e_ac, e_bc, e_mc, counts);
    scan_kernel<<<1, 1024, 0, stream>>>(counts, offs, cur);
    scatter_kernel<<<(NE_TOT + 255) / 256, 256, 0, stream>>>(e_ac, e_bc, e_mc, cur, sorted);

    // ---- dst-side + packed composite weights ----
    dim3 cg(NC / 4, 3);
    cellpart_kernel<<<cg, 256, 0, stream>>>(x_cell, Wf, bf, Ws, bs, Cf, Cs);
    dim3 wg(49, 3);
    wcomp_pack_kernel<<<wg, 256, 0, stream>>>(Wa, ba, Wb, bb, Wm, bm, Wf, Ws, wpA, wpB, wpM, bias);

    // ---- per relation: MFMA G + accum (G buffer reused) ----
    gmfma_kernel<92, 3><<<NA / 64, 256, 0, stream>>>(x_atom, wpA, bias + 0,   gbuf);
    accum_kernel<<<NC * 4 / 4, 256, 0, stream>>>(gbuf, sorted, offs, Cf, Cs, partial, 0);

    gmfma_kernel<7, 1><<<NB / 64, 256, 0, stream>>>(x_bond, wpB, bias + 128, gbuf);
    accum_kernel<<<NC * 4 / 4, 256, 0, stream>>>(gbuf, sorted, offs, Cf, Cs, partial, 1);

    gmfma_kernel<35, 2><<<NM / 64, 256, 0, stream>>>(x_motif, wpM, bias + 256, gbuf);
    accum_kernel<<<NC * 4 / 4, 256, 0, stream>>>(gbuf, sorted, offs, Cf, Cs, partial, 2);

    // ---- head ----
    head_kernel<<<NC / 4, 256, 0, stream>>>(partial, x_cell, Wp, bp, Wo, bo, out);
}

// Round 6
// 97.308 us; speedup vs baseline: 10.8036x; 1.3190x over previous
//
#include <hip/hip_runtime.h>
#include <hip/hip_fp16.h>

#define H 64
#define NA 65536
#define NB 131072
#define NM 16384
#define NC 2048
#define E_AC 65536
#define E_BC 131072
#define E_MC 16384
#define NE_TOT (E_AC + E_BC + E_MC)

#define CAPA 160
#define CAPB 224
#define CAPM 96
#define SLOTB (NC * CAPA)
#define SLOTM (SLOTB + NC * CAPB)
#define SLOT_TOT (SLOTM + NC * CAPM)

typedef __attribute__((ext_vector_type(8))) short bf16x8;
typedef __attribute__((ext_vector_type(4))) float f32x4;

__device__ __forceinline__ float sigmoidf_(float x) { return 1.0f / (1.0f + __expf(-x)); }
__device__ __forceinline__ float softplusf_(float x) {
    return fmaxf(x, 0.0f) + __logf(1.0f + __expf(-fabsf(x)));
}
__device__ __forceinline__ short bf16_of(float f) {
    union { float f; unsigned u; } v; v.f = f;
    unsigned r = (v.u + 0x7fff + ((v.u >> 16) & 1)) >> 16;  // RNE
    return (short)r;
}

// ================= K1: prep =================
// blocks [0,1536): cellpart Cf/Cs   [1536,1584): atom MFMA-pack
// 1584: atom bias   1585: zero cnt   [1586,1588): bond Wc   [1588,1597): motif Wc
__global__ __launch_bounds__(256) void prep_kernel(
    const float* __restrict__ xc,
    const float* __restrict__ Wf, const float* __restrict__ bf,
    const float* __restrict__ Ws, const float* __restrict__ bs,
    const float* __restrict__ Wa, const float* __restrict__ ba,
    const float* __restrict__ Wb, const float* __restrict__ bb_,
    const float* __restrict__ Wm, const float* __restrict__ bm,
    float* __restrict__ Cf, float* __restrict__ Cs,
    short* __restrict__ wpA, float* __restrict__ biasA,
    __half2* __restrict__ WcB, __half2* __restrict__ WcM, int* __restrict__ cnt)
{
    int b = blockIdx.x, tid = threadIdx.x;
    if (b < 1536) {
        __shared__ float Wl[2][H * H];
        int r = b >> 9, rowblk = b & 511;
        const float* WfT = Wf + (size_t)(6 + r) * 2 * H * H;
        const float* WsT = Ws + (size_t)(6 + r) * 2 * H * H;
        for (int i = tid; i < H * H; i += 256) { Wl[0][i] = WfT[i]; Wl[1][i] = WsT[i]; }
        __syncthreads();
        int row = rowblk * 4 + (tid >> 6), col = tid & 63;
        const float* xr = xc + (size_t)row * H;
        float af = bf[(6 + r) * H + col], as = bs[(6 + r) * H + col];
        #pragma unroll
        for (int k = 0; k < H; ++k) {
            float xv = xr[k];
            af = fmaf(xv, Wl[0][k * H + col], af);
            as = fmaf(xv, Wl[1][k * H + col], as);
        }
        Cf[((size_t)r * NC + row) * H + col] = af;
        Cs[((size_t)r * NC + row) * H + col] = as;
    } else if (b < 1584) {
        int idx = (b - 1536) * 256 + tid;          // < 96*128
        int k = idx >> 7, col = idx & 127, c = col & 63;
        const float* WB = ((col < 64) ? Wf : Ws) + (size_t)6 * 2 * H * H + (size_t)H * H;
        float v = 0.0f;
        if (k < 92) {
            const float* a = Wa + (size_t)k * H;
            for (int j = 0; j < H; ++j) v = fmaf(a[j], WB[j * H + c], v);
        }
        int t = col >> 4, lo = col & 15, sm = k >> 5, q = (k >> 3) & 3, e = k & 7;
        wpA[(size_t)(((t * 3 + sm) * 64) + q * 16 + lo) * 8 + e] = bf16_of(v);
    } else if (b == 1584) {
        if (tid < 128) {
            int col = tid, c = col & 63;
            const float* WB = ((col < 64) ? Wf : Ws) + (size_t)6 * 2 * H * H + (size_t)H * H;
            float v = 0.0f;
            for (int j = 0; j < H; ++j) v = fmaf(ba[j], WB[j * H + c], v);
            biasA[col] = v;
        }
    } else if (b == 1585) {
        for (int i = tid; i < 3 * NC; i += 256) cnt[i] = 0;
    } else if (b < 1588) {
        int idx = (b - 1586) * 256 + tid;
        if (idx < 8 * 64) {
            int k = idx >> 6, col = idx & 63;
            const float* WfB = Wf + (size_t)7 * 2 * H * H + (size_t)H * H;
            const float* WsB = Ws + (size_t)7 * 2 * H * H + (size_t)H * H;
            const float* row = (k < 7) ? (Wb + (size_t)k * H) : bb_;
            float f = 0.0f, s = 0.0f;
            for (int j = 0; j < H; ++j) {
                float rv = row[j];
                f = fmaf(rv, WfB[j * H + col], f);
                s = fmaf(rv, WsB[j * H + col], s);
            }
            WcB[k * 64 + col] = __floats2half2_rn(f, s);
        }
    } else {
        int idx = (b - 1588) * 256 + tid;
        if (idx < 36 * 64) {
            int k = idx >> 6, col = idx & 63;
            const float* WfB = Wf + (size_t)8 * 2 * H * H + (size_t)H * H;
            const float* WsB = Ws + (size_t)8 * 2 * H * H + (size_t)H * H;
            const float* row = (k < 35) ? (Wm + (size_t)k * H) : bm;
            float f = 0.0f, s = 0.0f;
            for (int j = 0; j < H; ++j) {
                float rv = row[j];
                f = fmaf(rv, WfB[j * H + col], f);
                s = fmaf(rv, WsB[j * H + col], s);
            }
            WcM[k * 64 + col] = __floats2half2_rn(f, s);
        }
    }
}

// ================= K2: atom G via MFMA + edge append =================
__global__ __launch_bounds__(256) void work2_kernel(
    const float* __restrict__ x, const short* __restrict__ wp,
    const float* __restrict__ bias, __half2* __restrict__ g,
    const int* __restrict__ ea, const int* __restrict__ eb, const int* __restrict__ em,
    int* __restrict__ cnt, int* __restrict__ slots)
{
    int b = blockIdx.x;
    if (b < 1024) {
        int l = threadIdx.x & 63;
        int wv = threadIdx.x >> 6;
        int r0 = (b * 4 + wv) * 16;
        int lrow = l & 15, q = l >> 4;

        bf16x8 bfrag[8][3];
        #pragma unroll
        for (int t = 0; t < 8; ++t)
            #pragma unroll
            for (int s = 0; s < 3; ++s)
                bfrag[t][s] = *(const bf16x8*)(wp + (size_t)((t * 3 + s) * 64 + l) * 8);

        float bF[4], bS[4];
        #pragma unroll
        for (int t = 0; t < 4; ++t) {
            bF[t] = bias[t * 16 + lrow];
            bS[t] = bias[64 + t * 16 + lrow];
        }

        f32x4 acc[8];
        #pragma unroll
        for (int t = 0; t < 8; ++t) acc[t] = (f32x4){0.f, 0.f, 0.f, 0.f};

        const float* xr = x + (size_t)(r0 + lrow) * 92;
        #pragma unroll
        for (int s = 0; s < 3; ++s) {
            int kb = s * 32 + q * 8;
            bf16x8 afrag;
            #pragma unroll
            for (int e = 0; e < 8; ++e) {
                float xv = 0.0f;
                if (kb + e < 92) xv = xr[kb + e];
                afrag[e] = bf16_of(xv);
            }
            #pragma unroll
            for (int t = 0; t < 8; ++t)
                acc[t] = __builtin_amdgcn_mfma_f32_16x16x32_bf16(afrag, bfrag[t][s], acc[t], 0, 0, 0);
        }

        #pragma unroll
        for (int t = 0; t < 4; ++t)
            #pragma unroll
            for (int r = 0; r < 4; ++r) {
                float fv = acc[t][r] + bF[t];
                float sv = acc[t + 4][r] + bS[t];
                g[(size_t)(r0 + q * 4 + r) * H + t * 16 + lrow] = __floats2half2_rn(fv, sv);
            }
    } else {
        int t = (b - 1024) * 256 + threadIdx.x;   // 0..26623
        #pragma unroll
        for (int u = 0; u < 8; ++u) {
            int i = t + u * 26624;
            int r, d, s;
            if (i < E_AC)             { r = 0; s = ea[i];                 d = ea[E_AC + i]; }
            else if (i < E_AC + E_BC) { int k = i - E_AC; r = 1; s = eb[k]; d = eb[E_BC + k]; }
            else                      { int k = i - E_AC - E_BC; r = 2; s = em[k]; d = em[E_MC + k]; }
            int pos = atomicAdd(&cnt[r * NC + d], 1);
            int base, cap;
            if (r == 0)      { base = d * CAPA;         cap = CAPA; }
            else if (r == 1) { base = SLOTB + d * CAPB; cap = CAPB; }
            else             { base = SLOTM + d * CAPM; cap = CAPM; }
            if (pos < cap) slots[base + pos] = s;
        }
    }
}

// ================= K3: accumulate all 3 relations =================
// blocks [0,2048): atom gather   [2048,4096): bond on-the-fly   [4096,5120): motif on-the-fly
__global__ __launch_bounds__(256) void accum_kernel(
    const __half2* __restrict__ g, const float* __restrict__ xb, const float* __restrict__ xm,
    const __half2* __restrict__ WcB, const __half2* __restrict__ WcM,
    const int* __restrict__ slots, const int* __restrict__ cnt,
    const float* __restrict__ Cf, const float* __restrict__ Cs,
    float* __restrict__ partial)
{
    int b = blockIdx.x;
    int lane = threadIdx.x & 63, wv = threadIdx.x >> 6;
    if (b < 2048) {
        int d = b, sub = wv;
        int n = min(cnt[d], CAPA);
        float cfv = Cf[(size_t)d * H + lane];
        float csv = Cs[(size_t)d * H + lane];
        const int* sl = slots + d * CAPA;
        float acc = 0.0f;
        int j = sub;
        for (; j + 12 < n; j += 16) {
            int i0 = sl[j], i1 = sl[j + 4], i2 = sl[j + 8], i3 = sl[j + 12];
            float2 a0 = __half22float2(g[(size_t)i0 * H + lane]);
            float2 a1 = __half22float2(g[(size_t)i1 * H + lane]);
            float2 a2 = __half22float2(g[(size_t)i2 * H + lane]);
            float2 a3 = __half22float2(g[(size_t)i3 * H + lane]);
            acc += sigmoidf_(cfv + a0.x) * softplusf_(csv + a0.y);
            acc += sigmoidf_(cfv + a1.x) * softplusf_(csv + a1.y);
            acc += sigmoidf_(cfv + a2.x) * softplusf_(csv + a2.y);
            acc += sigmoidf_(cfv + a3.x) * softplusf_(csv + a3.y);
        }
        for (; j < n; j += 4) {
            float2 a = __half22float2(g[(size_t)sl[j] * H + lane]);
            acc += sigmoidf_(cfv + a.x) * softplusf_(csv + a.y);
        }
        partial[((size_t)sub * NC + d) * H + lane] = acc;
    } else if (b < 4096) {
        int d = b - 2048, sub = wv;
        int n = min(cnt[NC + d], CAPB);
        float cfv = Cf[(size_t)(NC + d) * H + lane];
        float csv = Cs[(size_t)(NC + d) * H + lane];
        __half2 wc[8];
        #pragma unroll
        for (int k = 0; k < 8; ++k) wc[k] = WcB[k * 64 + lane];
        const int* sl = slots + SLOTB + d * CAPB;
        float acc = 0.0f;
        for (int j = sub; j < n; j += 4) {
            int s = sl[j];
            const float* xr = xb + (size_t)s * 7;
            float gf = __low2float(wc[7]), gs = __high2float(wc[7]);
            #pragma unroll
            for (int k = 0; k < 7; ++k) {
                float xv = xr[k];
                gf = fmaf(xv, __low2float(wc[k]), gf);
                gs = fmaf(xv, __high2float(wc[k]), gs);
            }
            acc += sigmoidf_(cfv + gf) * softplusf_(csv + gs);
        }
        partial[((size_t)(4 + sub) * NC + d) * H + lane] = acc;
    } else {
        int bb2 = b - 4096;
        int d = bb2 * 2 + (wv >> 1), sub = wv & 1;
        int n = min(cnt[2 * NC + d], CAPM);
        float cfv = Cf[(size_t)(2 * NC + d) * H + lane];
        float csv = Cs[(size_t)(2 * NC + d) * H + lane];
        __half2 wc[36];
        #pragma unroll
        for (int k = 0; k < 36; ++k) wc[k] = WcM[k * 64 + lane];
        const int* sl = slots + SLOTM + d * CAPM;
        float acc = 0.0f;
        for (int j = sub; j < n; j += 2) {
            int s = sl[j];
            const float* xr = xm + (size_t)s * 35;
            float gf = __low2float(wc[35]), gs = __high2float(wc[35]);
            #pragma unroll
            for (int k = 0; k < 35; ++k) {
                float xv = xr[k];
                gf = fmaf(xv, __low2float(wc[k]), gf);
                gs = fmaf(xv, __high2float(wc[k]), gs);
            }
            acc += sigmoidf_(cfv + gf) * softplusf_(csv + gs);
        }
        partial[((size_t)(8 + sub) * NC + d) * H + lane] = acc;
    }
}

// ================= K4: head =================
__global__ __launch_bounds__(256) void head_kernel(
    const float* __restrict__ partial, const float* __restrict__ xc,
    const float* __restrict__ Wp, const float* __restrict__ bp,
    const float* __restrict__ Wo, const float* __restrict__ bo,
    float* __restrict__ out)
{
    __shared__ float vL[4][H];
    int lane = threadIdx.x & 63;
    int w = threadIdx.x >> 6;
    int c = blockIdx.x * 4 + w;
    float a = 3.0f * xc[(size_t)c * H + lane];
    #pragma unroll
    for (int t = 0; t < 10; ++t) a += partial[((size_t)t * NC + c) * H + lane];
    vL[w][lane] = fmaxf(a, 0.0f);
    __syncthreads();
    float aj = bp[lane];
    #pragma unroll
    for (int k = 0; k < H; ++k) aj = fmaf(vL[w][k], Wp[k * H + lane], aj);
    float contrib = softplusf_(aj) * Wo[lane];
    #pragma unroll
    for (int o = 32; o > 0; o >>= 1) contrib += __shfl_down(contrib, o, 64);
    if (lane == 0) out[c] = contrib + bo[0];
}

extern "C" void kernel_launch(void* const* d_in, const int* in_sizes, int n_in,
                              void* d_out, int out_size, void* d_ws, size_t ws_size,
                              hipStream_t stream)
{
    const float* x_atom  = (const float*)d_in[0];
    const float* x_bond  = (const float*)d_in[1];
    const float* x_motif = (const float*)d_in[2];
    const float* x_cell  = (const float*)d_in[3];
    const float* Wa = (const float*)d_in[4];
    const float* ba = (const float*)d_in[5];
    const float* Wb = (const float*)d_in[6];
    const float* bb_ = (const float*)d_in[7];
    const float* Wm = (const float*)d_in[8];
    const float* bm = (const float*)d_in[9];
    const float* Wf = (const float*)d_in[10];
    const float* bf = (const float*)d_in[11];
    const float* Ws = (const float*)d_in[12];
    const float* bs = (const float*)d_in[13];
    const float* Wp = (const float*)d_in[14];
    const float* bp = (const float*)d_in[15];
    const float* Wo = (const float*)d_in[16];
    const float* bo = (const float*)d_in[17];
    const int* e_ac = (const int*)d_in[24];
    const int* e_bc = (const int*)d_in[25];
    const int* e_mc = (const int*)d_in[26];

    // ---- workspace layout (256B-aligned), ~29 MB ----
    char* base = (char*)d_ws;
    size_t o = 0;
    auto alloc = [&](size_t bytes) { char* r = base + o; o = (o + bytes + 255) & ~(size_t)255; return r; };
    float*   Cf      = (float*)  alloc(3 * NC * H * sizeof(float));
    float*   Cs      = (float*)  alloc(3 * NC * H * sizeof(float));
    float*   partial = (float*)  alloc(10 * NC * H * sizeof(float));
    int*     cnt     = (int*)    alloc(3 * NC * sizeof(int));
    int*     slots   = (int*)    alloc(SLOT_TOT * sizeof(int));
    short*   wpA     = (short*)  alloc(8 * 3 * 64 * 8 * sizeof(short));
    float*   biasA   = (float*)  alloc(128 * sizeof(float));
    __half2* WcB     = (__half2*)alloc(8 * 64 * sizeof(__half2));
    __half2* WcM     = (__half2*)alloc(36 * 64 * sizeof(__half2));
    __half2* gbufA   = (__half2*)alloc((size_t)NA * H * sizeof(__half2));  // 16.8 MB
    float*   out     = (float*)d_out;

    prep_kernel<<<1597, 256, 0, stream>>>(x_cell, Wf, bf, Ws, bs, Wa, ba, Wb, bb_, Wm, bm,
                                          Cf, Cs, wpA, biasA, WcB, WcM, cnt);
    work2_kernel<<<1128, 256, 0, stream>>>(x_atom, wpA, biasA, gbufA,
                                           e_ac, e_bc, e_mc, cnt, slots);
    accum_kernel<<<5120, 256, 0, stream>>>(gbufA, x_bond, x_motif, WcB, WcM,
                                           slots, cnt, Cf, Cs, partial);
    head_kernel<<<NC / 4, 256, 0, stream>>>(partial, x_cell, Wp, bp, Wo, bo, out);
}

// Round 7
// 89.305 us; speedup vs baseline: 11.7717x; 1.0896x over previous
//
#include <hip/hip_runtime.h>
#include <hip/hip_fp16.h>

#define H 64
#define NA 65536
#define NB 131072
#define NM 16384
#define NC 2048
#define E_AC 65536
#define E_BC 131072
#define E_MC 16384
#define NE_TOT (E_AC + E_BC + E_MC)

#define CAPA 160
#define CAPB 224
#define CAPM 96
#define SLOTB (NC * CAPA)
#define SLOTM (SLOTB + NC * CAPB)
#define SLOT_TOT (SLOTM + NC * CAPM)

typedef __attribute__((ext_vector_type(8))) short bf16x8;
typedef __attribute__((ext_vector_type(4))) float f32x4;

__device__ __forceinline__ float sigmoidf_(float x) { return 1.0f / (1.0f + __expf(-x)); }
__device__ __forceinline__ float softplusf_(float x) {
    return fmaxf(x, 0.0f) + __logf(1.0f + __expf(-fabsf(x)));
}
__device__ __forceinline__ short bf16_of(float f) {
    union { float f; unsigned u; } v; v.f = f;
    unsigned r = (v.u + 0x7fff + ((v.u >> 16) & 1)) >> 16;  // RNE
    return (short)r;
}

// ================= K1: prep =================
// [0,384): cellpart (16 rows/blk)  [384,432): atom MFMA-pack  [432,464): motif MFMA-pack
// 464: biasA  465: biasM  [466,468): bond Wc  [468,572): edge append
__global__ __launch_bounds__(256) void prep_kernel(
    const float* __restrict__ xc,
    const float* __restrict__ Wf, const float* __restrict__ bf,
    const float* __restrict__ Ws, const float* __restrict__ bs,
    const float* __restrict__ Wa, const float* __restrict__ ba,
    const float* __restrict__ Wb, const float* __restrict__ bb_,
    const float* __restrict__ Wm, const float* __restrict__ bm,
    const int* __restrict__ ea, const int* __restrict__ eb, const int* __restrict__ em,
    float* __restrict__ Cf, float* __restrict__ Cs,
    short* __restrict__ wpA, short* __restrict__ wpM,
    float* __restrict__ biasA, float* __restrict__ biasM,
    __half2* __restrict__ WcB,
    int* __restrict__ cnt, int* __restrict__ slots)
{
    int b = blockIdx.x, tid = threadIdx.x;
    if (b < 384) {
        __shared__ float Wl[2][H * H];
        int r = b / 128, rowblk = b % 128;
        const float* WfT = Wf + (size_t)(6 + r) * 2 * H * H;
        const float* WsT = Ws + (size_t)(6 + r) * 2 * H * H;
        for (int i = tid; i < H * H; i += 256) { Wl[0][i] = WfT[i]; Wl[1][i] = WsT[i]; }
        __syncthreads();
        int col = tid & 63, rgrp = tid >> 6;
        float bfv = bf[(6 + r) * H + col], bsv = bs[(6 + r) * H + col];
        #pragma unroll
        for (int rr = 0; rr < 4; ++rr) {
            int row = rowblk * 16 + rgrp * 4 + rr;
            const float* xr = xc + (size_t)row * H;
            float af = bfv, as = bsv;
            #pragma unroll
            for (int k = 0; k < H; ++k) {
                float xv = xr[k];
                af = fmaf(xv, Wl[0][k * H + col], af);
                as = fmaf(xv, Wl[1][k * H + col], as);
            }
            Cf[((size_t)r * NC + row) * H + col] = af;
            Cs[((size_t)r * NC + row) * H + col] = as;
        }
    } else if (b < 432) {
        int idx = (b - 384) * 256 + tid;           // < 96*128
        int k = idx >> 7, col = idx & 127, c = col & 63;
        const float* WB = ((col < 64) ? Wf : Ws) + (size_t)6 * 2 * H * H + (size_t)H * H;
        float v = 0.0f;
        if (k < 92) {
            const float* a = Wa + (size_t)k * H;
            for (int j = 0; j < H; ++j) v = fmaf(a[j], WB[j * H + c], v);
        }
        int t = col >> 4, lo = col & 15, sm = k >> 5, q = (k >> 3) & 3, e = k & 7;
        wpA[(size_t)(((t * 3 + sm) * 64) + q * 16 + lo) * 8 + e] = bf16_of(v);
    } else if (b < 464) {
        int idx = (b - 432) * 256 + tid;           // < 64*128
        int k = idx >> 7, col = idx & 127, c = col & 63;
        const float* WB = ((col < 64) ? Wf : Ws) + (size_t)8 * 2 * H * H + (size_t)H * H;
        float v = 0.0f;
        if (k < 35) {
            const float* a = Wm + (size_t)k * H;
            for (int j = 0; j < H; ++j) v = fmaf(a[j], WB[j * H + c], v);
        }
        int t = col >> 4, lo = col & 15, sm = k >> 5, q = (k >> 3) & 3, e = k & 7;
        wpM[(size_t)(((t * 2 + sm) * 64) + q * 16 + lo) * 8 + e] = bf16_of(v);
    } else if (b == 464) {
        if (tid < 128) {
            int col = tid, c = col & 63;
            const float* WB = ((col < 64) ? Wf : Ws) + (size_t)6 * 2 * H * H + (size_t)H * H;
            float v = 0.0f;
            for (int j = 0; j < H; ++j) v = fmaf(ba[j], WB[j * H + c], v);
            biasA[col] = v;
        }
    } else if (b == 465) {
        if (tid < 128) {
            int col = tid, c = col & 63;
            const float* WB = ((col < 64) ? Wf : Ws) + (size_t)8 * 2 * H * H + (size_t)H * H;
            float v = 0.0f;
            for (int j = 0; j < H; ++j) v = fmaf(bm[j], WB[j * H + c], v);
            biasM[col] = v;
        }
    } else if (b < 468) {
        int idx = (b - 466) * 256 + tid;
        if (idx < 8 * 64) {
            int k = idx >> 6, col = idx & 63;
            const float* WfB = Wf + (size_t)7 * 2 * H * H + (size_t)H * H;
            const float* WsB = Ws + (size_t)7 * 2 * H * H + (size_t)H * H;
            const float* row = (k < 7) ? (Wb + (size_t)k * H) : bb_;
            float f = 0.0f, s = 0.0f;
            for (int j = 0; j < H; ++j) {
                float rv = row[j];
                f = fmaf(rv, WfB[j * H + col], f);
                s = fmaf(rv, WsB[j * H + col], s);
            }
            WcB[k * 64 + col] = __floats2half2_rn(f, s);
        }
    } else {
        int t = (b - 468) * 256 + tid;             // 0..26623
        #pragma unroll
        for (int u = 0; u < 8; ++u) {
            int i = t + u * 26624;
            int r, d, s;
            if (i < E_AC)             { r = 0; s = ea[i];                 d = ea[E_AC + i]; }
            else if (i < E_AC + E_BC) { int k = i - E_AC; r = 1; s = eb[k]; d = eb[E_BC + k]; }
            else                      { int k = i - E_AC - E_BC; r = 2; s = em[k]; d = em[E_MC + k]; }
            int pos = atomicAdd(&cnt[r * NC + d], 1);
            int base, cap;
            if (r == 0)      { base = d * CAPA;         cap = CAPA; }
            else if (r == 1) { base = SLOTB + d * CAPB; cap = CAPB; }
            else             { base = SLOTM + d * CAPM; cap = CAPM; }
            if (pos < cap) slots[base + pos] = s;
        }
    }
}

// ================= K2: G build via MFMA (atom + motif) =================
template<int K, int S>
__device__ __forceinline__ void gmfma_body(
    int blk, const float* __restrict__ x, const short* __restrict__ wp,
    const float* __restrict__ bias, __half2* __restrict__ g)
{
    int l = threadIdx.x & 63;
    int wv = threadIdx.x >> 6;
    int r0 = (blk * 4 + wv) * 16;
    int lrow = l & 15, q = l >> 4;

    bf16x8 bfrag[8][S];
    #pragma unroll
    for (int t = 0; t < 8; ++t)
        #pragma unroll
        for (int s = 0; s < S; ++s)
            bfrag[t][s] = *(const bf16x8*)(wp + (size_t)((t * S + s) * 64 + l) * 8);

    float bF[4], bS[4];
    #pragma unroll
    for (int t = 0; t < 4; ++t) {
        bF[t] = bias[t * 16 + lrow];
        bS[t] = bias[64 + t * 16 + lrow];
    }

    f32x4 acc[8];
    #pragma unroll
    for (int t = 0; t < 8; ++t) acc[t] = (f32x4){0.f, 0.f, 0.f, 0.f};

    const float* xr = x + (size_t)(r0 + lrow) * K;
    #pragma unroll
    for (int s = 0; s < S; ++s) {
        int kb = s * 32 + q * 8;
        bf16x8 afrag;
        #pragma unroll
        for (int e = 0; e < 8; ++e) {
            float xv = 0.0f;
            if (kb + e < K) xv = xr[kb + e];
            afrag[e] = bf16_of(xv);
        }
        #pragma unroll
        for (int t = 0; t < 8; ++t)
            acc[t] = __builtin_amdgcn_mfma_f32_16x16x32_bf16(afrag, bfrag[t][s], acc[t], 0, 0, 0);
    }

    #pragma unroll
    for (int t = 0; t < 4; ++t)
        #pragma unroll
        for (int r = 0; r < 4; ++r) {
            float fv = acc[t][r] + bF[t];
            float sv = acc[t + 4][r] + bS[t];
            g[(size_t)(r0 + q * 4 + r) * H + t * 16 + lrow] = __floats2half2_rn(fv, sv);
        }
}

__global__ __launch_bounds__(256) void gbuild_kernel(
    const float* __restrict__ xa, const short* __restrict__ wpA, const float* __restrict__ biasA,
    __half2* __restrict__ gA,
    const float* __restrict__ xm, const short* __restrict__ wpM, const float* __restrict__ biasM,
    __half2* __restrict__ gM)
{
    if (blockIdx.x < 1024) gmfma_body<92, 3>(blockIdx.x, xa, wpA, biasA, gA);
    else                   gmfma_body<35, 2>(blockIdx.x - 1024, xm, wpM, biasM, gM);
}

// ================= K3: accumulate =================
// [0,4096): atom (2 blk/bucket, 8 subs)  [4096,12288): bond (4 blk/bucket, 16 subs)
// [12288,14336): motif (1 blk/bucket, 4 subs). Block-level LDS reduce -> 7 partial slices.
__global__ __launch_bounds__(256) void accum_kernel(
    const __half2* __restrict__ gA, const __half2* __restrict__ gM,
    const float* __restrict__ xb, const __half2* __restrict__ WcB,
    const int* __restrict__ slots, const int* __restrict__ cnt,
    const float* __restrict__ Cf, const float* __restrict__ Cs,
    float* __restrict__ partial)
{
    __shared__ float red[4][H];
    int b = blockIdx.x;
    int lane = threadIdx.x & 63, wv = threadIdx.x >> 6;
    float acc = 0.0f;
    int d, slice;

    if (b < 4096) {
        d = b >> 1;
        int sub = (b & 1) * 4 + wv;                 // 8 subs
        slice = b & 1;
        int n = min(cnt[d], CAPA);
        float cfv = Cf[(size_t)d * H + lane];
        float csv = Cs[(size_t)d * H + lane];
        const int* sl = slots + d * CAPA;
        for (int j = sub; j < n; j += 32) {
            int idx[4]; float msk[4];
            #pragma unroll
            for (int v = 0; v < 4; ++v) {
                int jc = j + v * 8;
                msk[v] = (jc < n) ? 1.0f : 0.0f;
                idx[v] = sl[min(jc, n - 1)];
            }
            #pragma unroll
            for (int v = 0; v < 4; ++v) {
                float2 a = __half22float2(gA[(size_t)idx[v] * H + lane]);
                acc += msk[v] * (sigmoidf_(cfv + a.x) * softplusf_(csv + a.y));
            }
        }
    } else if (b < 12288) {
        int v2 = b - 4096;
        d = v2 >> 2;
        int sub = (v2 & 3) * 4 + wv;                // 16 subs
        slice = 2 + (v2 & 3);
        int n = min(cnt[NC + d], CAPB);
        float cfv = Cf[(size_t)(NC + d) * H + lane];
        float csv = Cs[(size_t)(NC + d) * H + lane];
        __half2 wc[8];
        #pragma unroll
        for (int k = 0; k < 8; ++k) wc[k] = WcB[k * 64 + lane];
        const int* sl = slots + SLOTB + d * CAPB;
        for (int j = sub; j < n; j += 64) {
            int idx[4]; float msk[4];
            #pragma unroll
            for (int v = 0; v < 4; ++v) {
                int jc = j + v * 16;
                msk[v] = (jc < n) ? 1.0f : 0.0f;
                idx[v] = sl[min(jc, n - 1)];
            }
            float xr[4][7];
            #pragma unroll
            for (int v = 0; v < 4; ++v) {
                const float* p = xb + (size_t)idx[v] * 7;
                #pragma unroll
                for (int k = 0; k < 7; ++k) xr[v][k] = p[k];
            }
            #pragma unroll
            for (int v = 0; v < 4; ++v) {
                float gf = __low2float(wc[7]), gs = __high2float(wc[7]);
                #pragma unroll
                for (int k = 0; k < 7; ++k) {
                    gf = fmaf(xr[v][k], __low2float(wc[k]), gf);
                    gs = fmaf(xr[v][k], __high2float(wc[k]), gs);
                }
                acc += msk[v] * (sigmoidf_(cfv + gf) * softplusf_(csv + gs));
            }
        }
    } else {
        d = b - 12288;
        int sub = wv;                                // 4 subs
        slice = 6;
        int n = min(cnt[2 * NC + d], CAPM);
        float cfv = Cf[(size_t)(2 * NC + d) * H + lane];
        float csv = Cs[(size_t)(2 * NC + d) * H + lane];
        const int* sl = slots + SLOTM + d * CAPM;
        for (int j = sub; j < n; j += 16) {
            int idx[4]; float msk[4];
            #pragma unroll
            for (int v = 0; v < 4; ++v) {
                int jc = j + v * 4;
                msk[v] = (jc < n) ? 1.0f : 0.0f;
                idx[v] = sl[min(jc, n - 1)];
            }
            #pragma unroll
            for (int v = 0; v < 4; ++v) {
                float2 a = __half22float2(gM[(size_t)idx[v] * H + lane]);
                acc += msk[v] * (sigmoidf_(cfv + a.x) * softplusf_(csv + a.y));
            }
        }
    }

    red[wv][lane] = acc;
    __syncthreads();
    if (wv == 0) {
        float s = red[0][lane] + red[1][lane] + red[2][lane] + red[3][lane];
        partial[((size_t)slice * NC + d) * H + lane] = s;
    }
}

// ================= K4: head =================
__global__ __launch_bounds__(256) void head_kernel(
    const float* __restrict__ partial, const float* __restrict__ xc,
    const float* __restrict__ Wp, const float* __restrict__ bp,
    const float* __restrict__ Wo, const float* __restrict__ bo,
    float* __restrict__ out)
{
    __shared__ float vL[4][H];
    int lane = threadIdx.x & 63;
    int w = threadIdx.x >> 6;
    int c = blockIdx.x * 4 + w;
    float a = 3.0f * xc[(size_t)c * H + lane];
    #pragma unroll
    for (int t = 0; t < 7; ++t) a += partial[((size_t)t * NC + c) * H + lane];
    vL[w][lane] = fmaxf(a, 0.0f);
    __syncthreads();
    float aj = bp[lane];
    #pragma unroll
    for (int k = 0; k < H; ++k) aj = fmaf(vL[w][k], Wp[k * H + lane], aj);
    float contrib = softplusf_(aj) * Wo[lane];
    #pragma unroll
    for (int o = 32; o > 0; o >>= 1) contrib += __shfl_down(contrib, o, 64);
    if (lane == 0) out[c] = contrib + bo[0];
}

extern "C" void kernel_launch(void* const* d_in, const int* in_sizes, int n_in,
                              void* d_out, int out_size, void* d_ws, size_t ws_size,
                              hipStream_t stream)
{
    const float* x_atom  = (const float*)d_in[0];
    const float* x_bond  = (const float*)d_in[1];
    const float* x_motif = (const float*)d_in[2];
    const float* x_cell  = (const float*)d_in[3];
    const float* Wa = (const float*)d_in[4];
    const float* ba = (const float*)d_in[5];
    const float* Wb = (const float*)d_in[6];
    const float* bb_ = (const float*)d_in[7];
    const float* Wm = (const float*)d_in[8];
    const float* bm = (const float*)d_in[9];
    const float* Wf = (const float*)d_in[10];
    const float* bf = (const float*)d_in[11];
    const float* Ws = (const float*)d_in[12];
    const float* bs = (const float*)d_in[13];
    const float* Wp = (const float*)d_in[14];
    const float* bp = (const float*)d_in[15];
    const float* Wo = (const float*)d_in[16];
    const float* bo = (const float*)d_in[17];
    const int* e_ac = (const int*)d_in[24];
    const int* e_bc = (const int*)d_in[25];
    const int* e_mc = (const int*)d_in[26];

    // ---- workspace layout (256B-aligned), ~32 MB ----
    char* base = (char*)d_ws;
    size_t o = 0;
    auto alloc = [&](size_t bytes) { char* r = base + o; o = (o + bytes + 255) & ~(size_t)255; return r; };
    float*   Cf      = (float*)  alloc(3 * NC * H * sizeof(float));
    float*   Cs      = (float*)  alloc(3 * NC * H * sizeof(float));
    float*   partial = (float*)  alloc(7 * NC * H * sizeof(float));
    int*     cnt     = (int*)    alloc(3 * NC * sizeof(int));
    int*     slots   = (int*)    alloc(SLOT_TOT * sizeof(int));
    short*   wpA     = (short*)  alloc(8 * 3 * 64 * 8 * sizeof(short));
    short*   wpM     = (short*)  alloc(8 * 2 * 64 * 8 * sizeof(short));
    float*   biasA   = (float*)  alloc(128 * sizeof(float));
    float*   biasM   = (float*)  alloc(128 * sizeof(float));
    __half2* WcB     = (__half2*)alloc(8 * 64 * sizeof(__half2));
    __half2* gA      = (__half2*)alloc((size_t)NA * H * sizeof(__half2));  // 16.8 MB
    __half2* gM      = (__half2*)alloc((size_t)NM * H * sizeof(__half2));  // 4.2 MB
    float*   out     = (float*)d_out;

    hipMemsetAsync(cnt, 0, 3 * NC * sizeof(int), stream);
    prep_kernel<<<572, 256, 0, stream>>>(x_cell, Wf, bf, Ws, bs, Wa, ba, Wb, bb_, Wm, bm,
                                         e_ac, e_bc, e_mc,
                                         Cf, Cs, wpA, wpM, biasA, biasM, WcB, cnt, slots);
    gbuild_kernel<<<1280, 256, 0, stream>>>(x_atom, wpA, biasA, gA, x_motif, wpM, biasM, gM);
    accum_kernel<<<14336, 256, 0, stream>>>(gA, gM, x_bond, WcB, slots, cnt, Cf, Cs, partial);
    head_kernel<<<NC / 4, 256, 0, stream>>>(partial, x_cell, Wp, bp, Wo, bo, out);
}

// Round 8
// 85.896 us; speedup vs baseline: 12.2390x; 1.0397x over previous
//
#include <hip/hip_runtime.h>
#include <hip/hip_fp16.h>

#define H 64
#define NA 65536
#define NB 131072
#define NM 16384
#define NC 2048
#define E_AC 65536
#define E_BC 131072
#define E_MC 16384
#define NE_TOT (E_AC + E_BC + E_MC)

#define CAPA 160
#define CAPB 224
#define CAPM 96
#define SLOTB (NC * CAPA)
#define SLOTM (SLOTB + NC * CAPB)
#define SLOT_TOT (SLOTM + NC * CAPM)

typedef __attribute__((ext_vector_type(8))) short bf16x8;
typedef __attribute__((ext_vector_type(4))) float f32x4;

__device__ __forceinline__ float sigmoidf_(float x) { return 1.0f / (1.0f + __expf(-x)); }
__device__ __forceinline__ float softplusf_(float x) {
    return fmaxf(x, 0.0f) + __logf(1.0f + __expf(-fabsf(x)));
}
__device__ __forceinline__ short bf16_of(float f) {
    union { float f; unsigned u; } v; v.f = f;
    unsigned r = (v.u + 0x7fff + ((v.u >> 16) & 1)) >> 16;  // RNE
    return (short)r;
}

// ================= K1: prep =================
// [0,384): cellpart (16 rows/blk)  [384,432): atom MFMA-pack  [432,464): motif MFMA-pack
// 464: biasA  465: biasM  [466,468): bond Wc  [468,572): edge append
__global__ __launch_bounds__(256) void prep_kernel(
    const float* __restrict__ xc,
    const float* __restrict__ Wf, const float* __restrict__ bf,
    const float* __restrict__ Ws, const float* __restrict__ bs,
    const float* __restrict__ Wa, const float* __restrict__ ba,
    const float* __restrict__ Wb, const float* __restrict__ bb_,
    const float* __restrict__ Wm, const float* __restrict__ bm,
    const int* __restrict__ ea, const int* __restrict__ eb, const int* __restrict__ em,
    float* __restrict__ Cf, float* __restrict__ Cs,
    short* __restrict__ wpA, short* __restrict__ wpM,
    float* __restrict__ biasA, float* __restrict__ biasM,
    __half2* __restrict__ WcB,
    int* __restrict__ cnt, int* __restrict__ slots)
{
    int b = blockIdx.x, tid = threadIdx.x;
    if (b < 384) {
        __shared__ float Wl[2][H * H];
        int r = b / 128, rowblk = b % 128;
        const float* WfT = Wf + (size_t)(6 + r) * 2 * H * H;
        const float* WsT = Ws + (size_t)(6 + r) * 2 * H * H;
        for (int i = tid; i < H * H; i += 256) { Wl[0][i] = WfT[i]; Wl[1][i] = WsT[i]; }
        __syncthreads();
        int col = tid & 63, rgrp = tid >> 6;
        float bfv = bf[(6 + r) * H + col], bsv = bs[(6 + r) * H + col];
        #pragma unroll
        for (int rr = 0; rr < 4; ++rr) {
            int row = rowblk * 16 + rgrp * 4 + rr;
            const float* xr = xc + (size_t)row * H;
            float af = bfv, as = bsv;
            #pragma unroll
            for (int k = 0; k < H; ++k) {
                float xv = xr[k];
                af = fmaf(xv, Wl[0][k * H + col], af);
                as = fmaf(xv, Wl[1][k * H + col], as);
            }
            Cf[((size_t)r * NC + row) * H + col] = af;
            Cs[((size_t)r * NC + row) * H + col] = as;
        }
    } else if (b < 432) {
        int idx = (b - 384) * 256 + tid;           // < 96*128
        int k = idx >> 7, col = idx & 127, c = col & 63;
        const float* WB = ((col < 64) ? Wf : Ws) + (size_t)6 * 2 * H * H + (size_t)H * H;
        float v = 0.0f;
        if (k < 92) {
            const float* a = Wa + (size_t)k * H;
            for (int j = 0; j < H; ++j) v = fmaf(a[j], WB[j * H + c], v);
        }
        int t = col >> 4, lo = col & 15, sm = k >> 5, q = (k >> 3) & 3, e = k & 7;
        wpA[(size_t)(((t * 3 + sm) * 64) + q * 16 + lo) * 8 + e] = bf16_of(v);
    } else if (b < 464) {
        int idx = (b - 432) * 256 + tid;           // < 64*128
        int k = idx >> 7, col = idx & 127, c = col & 63;
        const float* WB = ((col < 64) ? Wf : Ws) + (size_t)8 * 2 * H * H + (size_t)H * H;
        float v = 0.0f;
        if (k < 35) {
            const float* a = Wm + (size_t)k * H;
            for (int j = 0; j < H; ++j) v = fmaf(a[j], WB[j * H + c], v);
        }
        int t = col >> 4, lo = col & 15, sm = k >> 5, q = (k >> 3) & 3, e = k & 7;
        wpM[(size_t)(((t * 2 + sm) * 64) + q * 16 + lo) * 8 + e] = bf16_of(v);
    } else if (b == 464) {
        if (tid < 128) {
            int col = tid, c = col & 63;
            const float* WB = ((col < 64) ? Wf : Ws) + (size_t)6 * 2 * H * H + (size_t)H * H;
            float v = 0.0f;
            for (int j = 0; j < H; ++j) v = fmaf(ba[j], WB[j * H + c], v);
            biasA[col] = v;
        }
    } else if (b == 465) {
        if (tid < 128) {
            int col = tid, c = col & 63;
            const float* WB = ((col < 64) ? Wf : Ws) + (size_t)8 * 2 * H * H + (size_t)H * H;
            float v = 0.0f;
            for (int j = 0; j < H; ++j) v = fmaf(bm[j], WB[j * H + c], v);
            biasM[col] = v;
        }
    } else if (b < 468) {
        int idx = (b - 466) * 256 + tid;
        if (idx < 8 * 64) {
            int k = idx >> 6, col = idx & 63;
            const float* WfB = Wf + (size_t)7 * 2 * H * H + (size_t)H * H;
            const float* WsB = Ws + (size_t)7 * 2 * H * H + (size_t)H * H;
            const float* row = (k < 7) ? (Wb + (size_t)k * H) : bb_;
            float f = 0.0f, s = 0.0f;
            for (int j = 0; j < H; ++j) {
                float rv = row[j];
                f = fmaf(rv, WfB[j * H + col], f);
                s = fmaf(rv, WsB[j * H + col], s);
            }
            WcB[k * 64 + col] = __floats2half2_rn(f, s);
        }
    } else {
        int t = (b - 468) * 256 + tid;             // 0..26623
        #pragma unroll
        for (int u = 0; u < 8; ++u) {
            int i = t + u * 26624;
            int r, d, s;
            if (i < E_AC)             { r = 0; s = ea[i];                 d = ea[E_AC + i]; }
            else if (i < E_AC + E_BC) { int k = i - E_AC; r = 1; s = eb[k]; d = eb[E_BC + k]; }
            else                      { int k = i - E_AC - E_BC; r = 2; s = em[k]; d = em[E_MC + k]; }
            int pos = atomicAdd(&cnt[r * NC + d], 1);
            int base, cap;
            if (r == 0)      { base = d * CAPA;         cap = CAPA; }
            else if (r == 1) { base = SLOTB + d * CAPB; cap = CAPB; }
            else             { base = SLOTM + d * CAPM; cap = CAPM; }
            if (pos < cap) slots[base + pos] = s;
        }
    }
}

// ================= K2: G build via MFMA (atom + motif) =================
template<int K, int S>
__device__ __forceinline__ void gmfma_body(
    int blk, const float* __restrict__ x, const short* __restrict__ wp,
    const float* __restrict__ bias, __half2* __restrict__ g)
{
    int l = threadIdx.x & 63;
    int wv = threadIdx.x >> 6;
    int r0 = (blk * 4 + wv) * 16;
    int lrow = l & 15, q = l >> 4;

    bf16x8 bfrag[8][S];
    #pragma unroll
    for (int t = 0; t < 8; ++t)
        #pragma unroll
        for (int s = 0; s < S; ++s)
            bfrag[t][s] = *(const bf16x8*)(wp + (size_t)((t * S + s) * 64 + l) * 8);

    float bF[4], bS[4];
    #pragma unroll
    for (int t = 0; t < 4; ++t) {
        bF[t] = bias[t * 16 + lrow];
        bS[t] = bias[64 + t * 16 + lrow];
    }

    f32x4 acc[8];
    #pragma unroll
    for (int t = 0; t < 8; ++t) acc[t] = (f32x4){0.f, 0.f, 0.f, 0.f};

    const float* xr = x + (size_t)(r0 + lrow) * K;
    #pragma unroll
    for (int s = 0; s < S; ++s) {
        int kb = s * 32 + q * 8;
        bf16x8 afrag;
        #pragma unroll
        for (int e = 0; e < 8; ++e) {
            float xv = 0.0f;
            if (kb + e < K) xv = xr[kb + e];
            afrag[e] = bf16_of(xv);
        }
        #pragma unroll
        for (int t = 0; t < 8; ++t)
            acc[t] = __builtin_amdgcn_mfma_f32_16x16x32_bf16(afrag, bfrag[t][s], acc[t], 0, 0, 0);
    }

    #pragma unroll
    for (int t = 0; t < 4; ++t)
        #pragma unroll
        for (int r = 0; r < 4; ++r) {
            float fv = acc[t][r] + bF[t];
            float sv = acc[t + 4][r] + bS[t];
            g[(size_t)(r0 + q * 4 + r) * H + t * 16 + lrow] = __floats2half2_rn(fv, sv);
        }
}

__global__ __launch_bounds__(256) void gbuild_kernel(
    const float* __restrict__ xa, const short* __restrict__ wpA, const float* __restrict__ biasA,
    __half2* __restrict__ gA,
    const float* __restrict__ xm, const short* __restrict__ wpM, const float* __restrict__ biasM,
    __half2* __restrict__ gM)
{
    if (blockIdx.x < 1024) gmfma_body<92, 3>(blockIdx.x, xa, wpA, biasA, gA);
    else                   gmfma_body<35, 2>(blockIdx.x - 1024, xm, wpM, biasM, gM);
}

// ================= K3: per-cell accumulate + head (one block per cell) =================
__global__ __launch_bounds__(256) void cellacc_kernel(
    const __half2* __restrict__ gA, const __half2* __restrict__ gM,
    const float* __restrict__ xb, const __half2* __restrict__ WcB,
    const int* __restrict__ slots, const int* __restrict__ cnt,
    const float* __restrict__ Cf, const float* __restrict__ Cs,
    const float* __restrict__ xc,
    const float* __restrict__ Wp, const float* __restrict__ bp,
    const float* __restrict__ Wo, const float* __restrict__ bo,
    float* __restrict__ out)
{
    __shared__ float red[4][H];
    __shared__ float vL[H];
    int d = blockIdx.x;
    int lane = threadIdx.x & 63, wv = threadIdx.x >> 6;
    float acc = 0.0f;

    // ---- atom relation: gather gA ----
    {
        int n = min(cnt[d], CAPA);
        float cfv = Cf[(size_t)d * H + lane];
        float csv = Cs[(size_t)d * H + lane];
        const int* sl = slots + d * CAPA;
        for (int j = wv; j < n; j += 16) {
            int idx[4]; float msk[4];
            #pragma unroll
            for (int v = 0; v < 4; ++v) {
                int jc = j + 4 * v;
                msk[v] = (jc < n) ? 1.0f : 0.0f;
                idx[v] = sl[min(jc, n - 1)];
            }
            #pragma unroll
            for (int v = 0; v < 4; ++v) {
                float2 a = __half22float2(gA[(size_t)idx[v] * H + lane]);
                acc += msk[v] * (sigmoidf_(cfv + a.x) * softplusf_(csv + a.y));
            }
        }
    }
    // ---- bond relation: on-the-fly from x_bond with register composite weights ----
    {
        int n = min(cnt[NC + d], CAPB);
        float cfv = Cf[(size_t)(NC + d) * H + lane];
        float csv = Cs[(size_t)(NC + d) * H + lane];
        __half2 wc[8];
        #pragma unroll
        for (int k = 0; k < 8; ++k) wc[k] = WcB[k * 64 + lane];
        const int* sl = slots + SLOTB + d * CAPB;
        for (int j = wv; j < n; j += 16) {
            int idx[4]; float msk[4];
            #pragma unroll
            for (int v = 0; v < 4; ++v) {
                int jc = j + 4 * v;
                msk[v] = (jc < n) ? 1.0f : 0.0f;
                idx[v] = sl[min(jc, n - 1)];
            }
            float xr[4][7];
            #pragma unroll
            for (int v = 0; v < 4; ++v) {
                const float* p = xb + (size_t)idx[v] * 7;
                #pragma unroll
                for (int k = 0; k < 7; ++k) xr[v][k] = p[k];
            }
            #pragma unroll
            for (int v = 0; v < 4; ++v) {
                float gf = __low2float(wc[7]), gs = __high2float(wc[7]);
                #pragma unroll
                for (int k = 0; k < 7; ++k) {
                    gf = fmaf(xr[v][k], __low2float(wc[k]), gf);
                    gs = fmaf(xr[v][k], __high2float(wc[k]), gs);
                }
                acc += msk[v] * (sigmoidf_(cfv + gf) * softplusf_(csv + gs));
            }
        }
    }
    // ---- motif relation: gather gM ----
    {
        int n = min(cnt[2 * NC + d], CAPM);
        float cfv = Cf[(size_t)(2 * NC + d) * H + lane];
        float csv = Cs[(size_t)(2 * NC + d) * H + lane];
        const int* sl = slots + SLOTM + d * CAPM;
        for (int j = wv; j < n; j += 16) {
            int idx[4]; float msk[4];
            #pragma unroll
            for (int v = 0; v < 4; ++v) {
                int jc = j + 4 * v;
                msk[v] = (jc < n) ? 1.0f : 0.0f;
                idx[v] = sl[min(jc, n - 1)];
            }
            #pragma unroll
            for (int v = 0; v < 4; ++v) {
                float2 a = __half22float2(gM[(size_t)idx[v] * H + lane]);
                acc += msk[v] * (sigmoidf_(cfv + a.x) * softplusf_(csv + a.y));
            }
        }
    }

    red[wv][lane] = acc;
    __syncthreads();
    if (wv == 0) {
        float a = 3.0f * xc[(size_t)d * H + lane]
                + red[0][lane] + red[1][lane] + red[2][lane] + red[3][lane];
        vL[lane] = fmaxf(a, 0.0f);
        __builtin_amdgcn_s_waitcnt(0);   // wave-local LDS drain
        float aj = bp[lane];
        #pragma unroll
        for (int k = 0; k < H; ++k) aj = fmaf(vL[k], Wp[k * H + lane], aj);
        float contrib = softplusf_(aj) * Wo[lane];
        #pragma unroll
        for (int o = 32; o > 0; o >>= 1) contrib += __shfl_down(contrib, o, 64);
        if (lane == 0) out[d] = contrib + bo[0];
    }
}

extern "C" void kernel_launch(void* const* d_in, const int* in_sizes, int n_in,
                              void* d_out, int out_size, void* d_ws, size_t ws_size,
                              hipStream_t stream)
{
    const float* x_atom  = (const float*)d_in[0];
    const float* x_bond  = (const float*)d_in[1];
    const float* x_motif = (const float*)d_in[2];
    const float* x_cell  = (const float*)d_in[3];
    const float* Wa = (const float*)d_in[4];
    const float* ba = (const float*)d_in[5];
    const float* Wb = (const float*)d_in[6];
    const float* bb_ = (const float*)d_in[7];
    const float* Wm = (const float*)d_in[8];
    const float* bm = (const float*)d_in[9];
    const float* Wf = (const float*)d_in[10];
    const float* bf = (const float*)d_in[11];
    const float* Ws = (const float*)d_in[12];
    const float* bs = (const float*)d_in[13];
    const float* Wp = (const float*)d_in[14];
    const float* bp = (const float*)d_in[15];
    const float* Wo = (const float*)d_in[16];
    const float* bo = (const float*)d_in[17];
    const int* e_ac = (const int*)d_in[24];
    const int* e_bc = (const int*)d_in[25];
    const int* e_mc = (const int*)d_in[26];

    // ---- workspace layout (256B-aligned), ~28 MB ----
    char* base = (char*)d_ws;
    size_t o = 0;
    auto alloc = [&](size_t bytes) { char* r = base + o; o = (o + bytes + 255) & ~(size_t)255; return r; };
    float*   Cf      = (float*)  alloc(3 * NC * H * sizeof(float));
    float*   Cs      = (float*)  alloc(3 * NC * H * sizeof(float));
    int*     cnt     = (int*)    alloc(3 * NC * sizeof(int));
    int*     slots   = (int*)    alloc(SLOT_TOT * sizeof(int));
    short*   wpA     = (short*)  alloc(8 * 3 * 64 * 8 * sizeof(short));
    short*   wpM     = (short*)  alloc(8 * 2 * 64 * 8 * sizeof(short));
    float*   biasA   = (float*)  alloc(128 * sizeof(float));
    float*   biasM   = (float*)  alloc(128 * sizeof(float));
    __half2* WcB     = (__half2*)alloc(8 * 64 * sizeof(__half2));
    __half2* gA      = (__half2*)alloc((size_t)NA * H * sizeof(__half2));  // 16.8 MB
    __half2* gM      = (__half2*)alloc((size_t)NM * H * sizeof(__half2));  // 4.2 MB
    float*   out     = (float*)d_out;

    hipMemsetAsync(cnt, 0, 3 * NC * sizeof(int), stream);
    prep_kernel<<<572, 256, 0, stream>>>(x_cell, Wf, bf, Ws, bs, Wa, ba, Wb, bb_, Wm, bm,
                                         e_ac, e_bc, e_mc,
                                         Cf, Cs, wpA, wpM, biasA, biasM, WcB, cnt, slots);
    gbuild_kernel<<<1280, 256, 0, stream>>>(x_atom, wpA, biasA, gA, x_motif, wpM, biasM, gM);
    cellacc_kernel<<<NC, 256, 0, stream>>>(gA, gM, x_bond, WcB, slots, cnt, Cf, Cs,
                                           x_cell, Wp, bp, Wo, bo, out);
}